// Round 2
// baseline (6536.076 us; speedup 1.0000x reference)
//
#include <hip/hip_runtime.h>
#include <hip/hip_bf16.h>
#include <math.h>

// Problem dims
#define B_DIM 4
#define N_DIM 1024
#define D_DIM 1024
#define H_DIM 16
#define QK_DIM 64
#define HID_DIM 4096
#define BETA 0.125f
#define INV_BETA 8.0f

// ws layout (float offsets)
#define OFF_Q    0u          // [4096,1024]  Q  (b,n)x(h*64+q)
#define OFF_K    4194304u    // [4096,1024]  K
#define OFF_DQ   8388608u    // [4096,1024]  dQ
#define OFF_DK   12582912u   // [4096,1024]  dK
#define OFF_LSE  16777216u   // [B*H*N] = 65536
#define OFF_PL   16842752u   // lse partials [16384]
#define OFF_PH   16859136u   // hop-energy partials [1024]
#define OFF_WCT  16863232u   // WcatT [1024, 2048]  (d, j) j=cat(q-heads,k-heads)
#define OFF_WHT  18960384u   // WhopT [4096, 1024]  (e, d)
#define OFF_H    23154688u   // H bf16 [4096, 4096] (as 8388608 float slots)

// ---------------- transposes (once per launch, cheap) ----------------
__global__ void k_tcat(const float* __restrict__ Wq, const float* __restrict__ Wk,
                       float* __restrict__ WcatT) {
    __shared__ float t[32][33];
    int j0 = blockIdx.x * 32, d0 = blockIdx.y * 32;
    int tx = threadIdx.x, ty = threadIdx.y;
#pragma unroll
    for (int i = 0; i < 4; ++i) {
        int j = j0 + ty + 8 * i;
        const float* src = (j < 1024) ? (Wq + (size_t)j * 1024) : (Wk + (size_t)(j - 1024) * 1024);
        t[ty + 8 * i][tx] = src[d0 + tx];
    }
    __syncthreads();
#pragma unroll
    for (int i = 0; i < 4; ++i)
        WcatT[(size_t)(d0 + ty + 8 * i) * 2048 + j0 + tx] = t[tx][ty + 8 * i];
}

__global__ void k_thop(const float* __restrict__ Whop, float* __restrict__ WhopT) {
    __shared__ float t[32][33];
    int e0 = blockIdx.x * 32, d0 = blockIdx.y * 32;
    int tx = threadIdx.x, ty = threadIdx.y;
#pragma unroll
    for (int i = 0; i < 4; ++i)
        t[ty + 8 * i][tx] = Whop[(size_t)(d0 + ty + 8 * i) * 4096 + e0 + tx];
    __syncthreads();
#pragma unroll
    for (int i = 0; i < 4; ++i)
        WhopT[(size_t)(e0 + ty + 8 * i) * 1024 + d0 + tx] = t[tx][ty + 8 * i];
}

// ---------------- K1: Q/K projection (NT GEMM) ----------------
// C[m, j] = sum_d X[m,d] * W[j,d];  128x128 tile, 8x8/thread, BK=16
__global__ __launch_bounds__(256) void k_proj(const float* __restrict__ X,
                                              const float* __restrict__ Wq,
                                              const float* __restrict__ Wk,
                                              float* __restrict__ Qc,
                                              float* __restrict__ Kc) {
    __shared__ float As[128][20];
    __shared__ float Bs[128][20];
    const int tid = threadIdx.x;
    const int tx = tid & 15, ty = tid >> 4;
    const int rowBase = blockIdx.x * 128;
    const int byy = blockIdx.y;
    const float* Bsel = (byy < 8) ? Wq : Wk;
    float* Out = (byy < 8) ? Qc : Kc;
    const int colBase = (byy & 7) * 128;

    float acc[8][8];
#pragma unroll
    for (int i = 0; i < 8; ++i)
#pragma unroll
        for (int j = 0; j < 8; ++j) acc[i][j] = 0.f;

    for (int kk = 0; kk < 1024; kk += 16) {
#pragma unroll
        for (int L = 0; L < 2; ++L) {
            int p = tid + L * 256;
            int row = p >> 2, c4 = p & 3;
            *(float4*)&As[row][c4 * 4] =
                *(const float4*)&X[(size_t)(rowBase + row) * 1024 + kk + c4 * 4];
            *(float4*)&Bs[row][c4 * 4] =
                *(const float4*)&Bsel[(size_t)(colBase + row) * 1024 + kk + c4 * 4];
        }
        __syncthreads();
#pragma unroll
        for (int k4 = 0; k4 < 4; ++k4) {
            float4 a[8], b[8];
#pragma unroll
            for (int i = 0; i < 8; ++i) a[i] = *(const float4*)&As[ty + 16 * i][k4 * 4];
#pragma unroll
            for (int j = 0; j < 8; ++j) b[j] = *(const float4*)&Bs[tx + 16 * j][k4 * 4];
#pragma unroll
            for (int i = 0; i < 8; ++i)
#pragma unroll
                for (int j = 0; j < 8; ++j)
                    acc[i][j] += a[i].x * b[j].x + a[i].y * b[j].y + a[i].z * b[j].z + a[i].w * b[j].w;
        }
        __syncthreads();
    }
#pragma unroll
    for (int i = 0; i < 8; ++i) {
        size_t r = rowBase + ty + 16 * i;
#pragma unroll
        for (int j = 0; j < 8; ++j)
            Out[r * 1024 + colBase + tx + 16 * j] = acc[i][j];
    }
}

// ---------------- K2: row logsumexp ----------------
// 4 rows / block (one per wave); rows ordered r = (b*16+h)*1024 + n
__global__ __launch_bounds__(256) void k_lse(const float* __restrict__ Qc,
                                             const float* __restrict__ Kc,
                                             float* __restrict__ LSE,
                                             float* __restrict__ partials) {
    __shared__ float qs[4][64];
    __shared__ float Ks[64][68];
    __shared__ float red[4];
    const int tid = threadIdx.x, lane = tid & 63, w = tid >> 6;
    const int rbase = blockIdx.x * 4;
    const int b = rbase >> 14, h = (rbase >> 10) & 15, n0 = rbase & 1023;

    qs[w][lane] = Qc[((size_t)(b << 10) + n0 + w) * 1024 + h * 64 + lane];

    float mx = -INFINITY, sm = 0.f;
    for (int t = 0; t < 16; ++t) {
        __syncthreads();
#pragma unroll
        for (int i = 0; i < 4; ++i) {
            int p = tid + i * 256;
            int row = p >> 4, c4 = p & 15;
            *(float4*)&Ks[row][c4 * 4] =
                *(const float4*)&Kc[((size_t)(b << 10) + t * 64 + row) * 1024 + h * 64 + c4 * 4];
        }
        __syncthreads();
        float s = 0.f;
#pragma unroll
        for (int qq = 0; qq < 64; ++qq) {
            int q = (lane + qq) & 63;  // rotated start: conflict-free
            s += qs[w][q] * Ks[lane][q];
        }
        s *= BETA;
        float nm = fmaxf(mx, s);
        sm = sm * __expf(mx - nm) + __expf(s - nm);
        mx = nm;
    }
#pragma unroll
    for (int off = 32; off; off >>= 1) {
        float mx2 = __shfl_xor(mx, off);
        float sm2 = __shfl_xor(sm, off);
        float nm = fmaxf(mx, mx2);
        sm = sm * __expf(mx - nm) + sm2 * __expf(mx2 - nm);
        mx = nm;
    }
    float lse = mx + __logf(sm);
    if (lane == 0) {
        LSE[rbase + w] = lse;
        red[w] = lse;
    }
    __syncthreads();
    if (tid == 0) partials[blockIdx.x] = red[0] + red[1] + red[2] + red[3];
}

// ---------------- K3: dQ = -P K ----------------
__global__ __launch_bounds__(256) void k_dq(const float* __restrict__ Qc,
                                            const float* __restrict__ Kc,
                                            const float* __restrict__ LSE,
                                            float* __restrict__ dQc) {
    __shared__ float qs[4][64];
    __shared__ float Ks[64][68];
    __shared__ float ps[4][64];
    const int tid = threadIdx.x, lane = tid & 63, w = tid >> 6;
    const int rbase = blockIdx.x * 4;
    const int b = rbase >> 14, h = (rbase >> 10) & 15, n0 = rbase & 1023;

    qs[w][lane] = Qc[((size_t)(b << 10) + n0 + w) * 1024 + h * 64 + lane];
    const float lse = LSE[rbase + w];

    float dq = 0.f;
    for (int t = 0; t < 16; ++t) {
        __syncthreads();
#pragma unroll
        for (int i = 0; i < 4; ++i) {
            int p = tid + i * 256;
            int row = p >> 4, c4 = p & 15;
            *(float4*)&Ks[row][c4 * 4] =
                *(const float4*)&Kc[((size_t)(b << 10) + t * 64 + row) * 1024 + h * 64 + c4 * 4];
        }
        __syncthreads();
        float s = 0.f;
#pragma unroll
        for (int qq = 0; qq < 64; ++qq) {
            int q = (lane + qq) & 63;
            s += qs[w][q] * Ks[lane][q];
        }
        float p = __expf(s * BETA - lse);
        ps[w][lane] = p;
        __syncthreads();
        float d2 = 0.f;
#pragma unroll
        for (int mm = 0; mm < 64; ++mm) d2 += ps[w][mm] * Ks[mm][lane];
        dq += d2;
    }
    dQc[((size_t)(b << 10) + n0 + w) * 1024 + h * 64 + lane] = -dq;
}

// ---------------- K4: dK = -P^T Q ----------------
__global__ __launch_bounds__(256) void k_dk(const float* __restrict__ Qc,
                                            const float* __restrict__ Kc,
                                            const float* __restrict__ LSE,
                                            float* __restrict__ dKc) {
    __shared__ float ks[4][64];
    __shared__ float Qs[64][68];
    __shared__ float ps[4][64];
    __shared__ float lse_s[64];
    const int tid = threadIdx.x, lane = tid & 63, w = tid >> 6;
    const int rbase = blockIdx.x * 4;
    const int b = rbase >> 14, h = (rbase >> 10) & 15, m0 = rbase & 1023;
    const int base_bh = rbase - m0;

    ks[w][lane] = Kc[((size_t)(b << 10) + m0 + w) * 1024 + h * 64 + lane];

    float dk = 0.f;
    for (int t = 0; t < 16; ++t) {
        __syncthreads();
#pragma unroll
        for (int i = 0; i < 4; ++i) {
            int p = tid + i * 256;
            int row = p >> 4, c4 = p & 15;
            *(float4*)&Qs[row][c4 * 4] =
                *(const float4*)&Qc[((size_t)(b << 10) + t * 64 + row) * 1024 + h * 64 + c4 * 4];
        }
        if (tid < 64) lse_s[tid] = LSE[base_bh + t * 64 + tid];
        __syncthreads();
        float s = 0.f;
#pragma unroll
        for (int qq = 0; qq < 64; ++qq) {
            int q = (lane + qq) & 63;
            s += ks[w][q] * Qs[lane][q];
        }
        float p = __expf(s * BETA - lse_s[lane]);
        ps[w][lane] = p;
        __syncthreads();
        float d2 = 0.f;
#pragma unroll
        for (int nn = 0; nn < 64; ++nn) d2 += ps[w][nn] * Qs[nn][lane];
        dk += d2;
    }
    dKc[((size_t)(b << 10) + m0 + w) * 1024 + h * 64 + lane] = -dk;
}

// ---------------- K6: Hopfield forward H = relu(x Whop), e_hop partials ----------------
__global__ __launch_bounds__(256) void k_hopfwd(const float* __restrict__ X,
                                                const float* __restrict__ WhopT,
                                                __hip_bfloat16* __restrict__ Hm,
                                                float* __restrict__ partials) {
    __shared__ float As[128][20];
    __shared__ float Bs[128][20];
    __shared__ float red[4];
    const int tid = threadIdx.x;
    const int tx = tid & 15, ty = tid >> 4;
    const int rowBase = blockIdx.x * 128;
    const int colBase = blockIdx.y * 128;

    float acc[8][8];
#pragma unroll
    for (int i = 0; i < 8; ++i)
#pragma unroll
        for (int j = 0; j < 8; ++j) acc[i][j] = 0.f;

    for (int kk = 0; kk < 1024; kk += 16) {
#pragma unroll
        for (int L = 0; L < 2; ++L) {
            int p = tid + L * 256;
            int row = p >> 2, c4 = p & 3;
            *(float4*)&As[row][c4 * 4] =
                *(const float4*)&X[(size_t)(rowBase + row) * 1024 + kk + c4 * 4];
            *(float4*)&Bs[row][c4 * 4] =
                *(const float4*)&WhopT[(size_t)(colBase + row) * 1024 + kk + c4 * 4];
        }
        __syncthreads();
#pragma unroll
        for (int k4 = 0; k4 < 4; ++k4) {
            float4 a[8], b[8];
#pragma unroll
            for (int i = 0; i < 8; ++i) a[i] = *(const float4*)&As[ty + 16 * i][k4 * 4];
#pragma unroll
            for (int j = 0; j < 8; ++j) b[j] = *(const float4*)&Bs[tx + 16 * j][k4 * 4];
#pragma unroll
            for (int i = 0; i < 8; ++i)
#pragma unroll
                for (int j = 0; j < 8; ++j)
                    acc[i][j] += a[i].x * b[j].x + a[i].y * b[j].y + a[i].z * b[j].z + a[i].w * b[j].w;
        }
        __syncthreads();
    }
    float ss = 0.f;
#pragma unroll
    for (int i = 0; i < 8; ++i) {
        size_t r = rowBase + ty + 16 * i;
#pragma unroll
        for (int j = 0; j < 8; ++j) {
            float hv = fmaxf(acc[i][j], 0.f);
            ss += hv * hv;
            Hm[r * 4096 + colBase + tx + 16 * j] = __float2bfloat16(hv);
        }
    }
#pragma unroll
    for (int off = 32; off; off >>= 1) ss += __shfl_down(ss, off);
    if ((tid & 63) == 0) red[tid >> 6] = ss;
    __syncthreads();
    if (tid == 0) partials[blockIdx.y * gridDim.x + blockIdx.x] = red[0] + red[1] + red[2] + red[3];
}

// ---------------- K7: grad_hop = -H Whop^T  (pure write to out) ----------------
__global__ __launch_bounds__(256) void k_hopbwd(const unsigned short* __restrict__ Hm,
                                                const float* __restrict__ Whop,
                                                float* __restrict__ out) {
    __shared__ float As[128][20];
    __shared__ float Bs[128][20];
    const int tid = threadIdx.x;
    const int tx = tid & 15, ty = tid >> 4;
    const int rowBase = blockIdx.x * 128;
    const int colBase = blockIdx.y * 128;

    float acc[8][8];
#pragma unroll
    for (int i = 0; i < 8; ++i)
#pragma unroll
        for (int j = 0; j < 8; ++j) acc[i][j] = 0.f;

    for (int kk = 0; kk < 4096; kk += 16) {
#pragma unroll
        for (int L = 0; L < 2; ++L) {
            int p = tid + L * 256;
            int row = p >> 2, c4 = p & 3;
            ushort4 hv = *(const ushort4*)&Hm[(size_t)(rowBase + row) * 4096 + kk + c4 * 4];
            float4 af;
            af.x = __uint_as_float((unsigned)hv.x << 16);
            af.y = __uint_as_float((unsigned)hv.y << 16);
            af.z = __uint_as_float((unsigned)hv.z << 16);
            af.w = __uint_as_float((unsigned)hv.w << 16);
            *(float4*)&As[row][c4 * 4] = af;
            *(float4*)&Bs[row][c4 * 4] =
                *(const float4*)&Whop[(size_t)(colBase + row) * 4096 + kk + c4 * 4];
        }
        __syncthreads();
#pragma unroll
        for (int k4 = 0; k4 < 4; ++k4) {
            float4 a[8], b[8];
#pragma unroll
            for (int i = 0; i < 8; ++i) a[i] = *(const float4*)&As[ty + 16 * i][k4 * 4];
#pragma unroll
            for (int j = 0; j < 8; ++j) b[j] = *(const float4*)&Bs[tx + 16 * j][k4 * 4];
#pragma unroll
            for (int i = 0; i < 8; ++i)
#pragma unroll
                for (int j = 0; j < 8; ++j)
                    acc[i][j] += a[i].x * b[j].x + a[i].y * b[j].y + a[i].z * b[j].z + a[i].w * b[j].w;
        }
        __syncthreads();
    }
#pragma unroll
    for (int i = 0; i < 8; ++i) {
        size_t r = rowBase + ty + 16 * i;
#pragma unroll
        for (int j = 0; j < 8; ++j)
            out[r * 1024 + colBase + tx + 16 * j] = -acc[i][j];
    }
}

// ---------------- K5: out += dQ Wq + dK Wk  (NT via WcatT) ----------------
__global__ __launch_bounds__(256) void k_gradproj(const float* __restrict__ dQc,
                                                  const float* __restrict__ dKc,
                                                  const float* __restrict__ WcatT,
                                                  float* __restrict__ out) {
    __shared__ float As[128][20];
    __shared__ float Bs[128][20];
    const int tid = threadIdx.x;
    const int tx = tid & 15, ty = tid >> 4;
    const int rowBase = blockIdx.x * 128;
    const int colBase = blockIdx.y * 128;

    float acc[8][8];
#pragma unroll
    for (int i = 0; i < 8; ++i)
#pragma unroll
        for (int j = 0; j < 8; ++j) acc[i][j] = 0.f;

    for (int kk = 0; kk < 2048; kk += 16) {
        const float* Ap;
        int kloc;
        if (kk < 1024) { Ap = dQc; kloc = kk; } else { Ap = dKc; kloc = kk - 1024; }
#pragma unroll
        for (int L = 0; L < 2; ++L) {
            int p = tid + L * 256;
            int row = p >> 2, c4 = p & 3;
            *(float4*)&As[row][c4 * 4] =
                *(const float4*)&Ap[(size_t)(rowBase + row) * 1024 + kloc + c4 * 4];
            *(float4*)&Bs[row][c4 * 4] =
                *(const float4*)&WcatT[(size_t)(colBase + row) * 2048 + kk + c4 * 4];
        }
        __syncthreads();
#pragma unroll
        for (int k4 = 0; k4 < 4; ++k4) {
            float4 a[8], b[8];
#pragma unroll
            for (int i = 0; i < 8; ++i) a[i] = *(const float4*)&As[ty + 16 * i][k4 * 4];
#pragma unroll
            for (int j = 0; j < 8; ++j) b[j] = *(const float4*)&Bs[tx + 16 * j][k4 * 4];
#pragma unroll
            for (int i = 0; i < 8; ++i)
#pragma unroll
                for (int j = 0; j < 8; ++j)
                    acc[i][j] += a[i].x * b[j].x + a[i].y * b[j].y + a[i].z * b[j].z + a[i].w * b[j].w;
        }
        __syncthreads();
    }
#pragma unroll
    for (int i = 0; i < 8; ++i) {
        size_t r = rowBase + ty + 16 * i;
#pragma unroll
        for (int j = 0; j < 8; ++j) {
            size_t idx = r * 1024 + colBase + tx + 16 * j;
            out[idx] += acc[i][j];
        }
    }
}

// ---------------- K8: finalize energy ----------------
__global__ __launch_bounds__(256) void k_fin(const float* __restrict__ pl,
                                             const float* __restrict__ ph,
                                             float* __restrict__ out) {
    const int tid = threadIdx.x;
    float s1 = 0.f, s2 = 0.f;
    for (int i = tid; i < 16384; i += 256) s1 += pl[i];
    for (int i = tid; i < 1024; i += 256) s2 += ph[i];
#pragma unroll
    for (int off = 32; off; off >>= 1) {
        s1 += __shfl_down(s1, off);
        s2 += __shfl_down(s2, off);
    }
    __shared__ float r1[4], r2[4];
    if ((tid & 63) == 0) { r1[tid >> 6] = s1; r2[tid >> 6] = s2; }
    __syncthreads();
    if (tid == 0) {
        float S1 = r1[0] + r1[1] + r1[2] + r1[3];
        float S2 = r2[0] + r2[1] + r2[2] + r2[3];
        out[(size_t)4194304] = -INV_BETA * S1 - 0.5f * S2;
    }
}

extern "C" void kernel_launch(void* const* d_in, const int* in_sizes, int n_in,
                              void* d_out, int out_size, void* d_ws, size_t ws_size,
                              hipStream_t stream) {
    (void)in_sizes; (void)n_in; (void)out_size; (void)ws_size;
    const float* x    = (const float*)d_in[0];
    const float* Wq   = (const float*)d_in[1];
    const float* Wk   = (const float*)d_in[2];
    const float* Whop = (const float*)d_in[3];
    float* out = (float*)d_out;
    float* ws = (float*)d_ws;

    float* Qc    = ws + OFF_Q;
    float* Kc    = ws + OFF_K;
    float* dQc   = ws + OFF_DQ;
    float* dKc   = ws + OFF_DK;
    float* LSE   = ws + OFF_LSE;
    float* PL    = ws + OFF_PL;
    float* PH    = ws + OFF_PH;
    float* WcatT = ws + OFF_WCT;
    float* WhopT = ws + OFF_WHT;
    __hip_bfloat16* Hm = (__hip_bfloat16*)(ws + OFF_H);

    dim3 blk(256);
    k_tcat<<<dim3(64, 32), dim3(32, 8), 0, stream>>>(Wq, Wk, WcatT);
    k_thop<<<dim3(128, 32), dim3(32, 8), 0, stream>>>(Whop, WhopT);
    k_proj<<<dim3(32, 16), blk, 0, stream>>>(x, Wq, Wk, Qc, Kc);
    k_lse<<<dim3(16384), blk, 0, stream>>>(Qc, Kc, LSE, PL);
    k_dq<<<dim3(16384), blk, 0, stream>>>(Qc, Kc, LSE, dQc);
    k_dk<<<dim3(16384), blk, 0, stream>>>(Qc, Kc, LSE, dKc);
    k_hopfwd<<<dim3(32, 32), blk, 0, stream>>>(x, WhopT, Hm, PH);
    k_hopbwd<<<dim3(32, 8), blk, 0, stream>>>((const unsigned short*)Hm, Whop, out);
    k_gradproj<<<dim3(32, 8), blk, 0, stream>>>(dQc, dKc, WcatT, out);
    k_fin<<<dim3(1), blk, 0, stream>>>(PL, PH, out);
}

// Round 3
// 2503.927 us; speedup vs baseline: 2.6103x; 2.6103x over previous
//
#include <hip/hip_runtime.h>
#include <hip/hip_bf16.h>
#include <math.h>

#define BETA 0.125f
#define INV_BETA 8.0f

typedef __attribute__((ext_vector_type(8))) short short8v;
typedef __attribute__((ext_vector_type(4))) float f32x4;
typedef union { short8v v; unsigned short u[8]; } v8u;

// ws layout (float units)
#define OFF_DQ   0u          // f32 [4096][1024] cat layout
#define OFF_DK   4194304u    // f32 [4096][1024]
#define OFF_WCT  8388608u    // f32 WcatT [1024][2048]
#define OFF_WHT  10485760u   // f32 WhopT [4096][1024]
#define OFF_H    14680064u   // bf16 H [4096][4096] (8388608 float slots)
#define OFF_QB   23068672u   // bf16 Qb [64][1024][64] (2097152 float slots)
#define OFF_KB   25165824u   // bf16 Kb
#define OFF_QT   27262976u   // bf16 QT [64][64][1024]
#define OFF_KT   29360128u   // bf16 KT
#define OFF_LSE  31457280u   // f32 [65536]
#define OFF_PL   31522816u   // f32 [2048]
#define OFF_PH   31524864u   // f32 [1024]

__device__ __forceinline__ unsigned short f2b(float f) {
    unsigned u = __float_as_uint(f);
    return (unsigned short)((u + 0x7fffu + ((u >> 16) & 1u)) >> 16);
}

// ---------------- transposes for gradproj / hopfwd (f32, unchanged) ----------------
__global__ void k_tcat(const float* __restrict__ Wq, const float* __restrict__ Wk,
                       float* __restrict__ WcatT) {
    __shared__ float t[32][33];
    int j0 = blockIdx.x * 32, d0 = blockIdx.y * 32;
    int tx = threadIdx.x, ty = threadIdx.y;
#pragma unroll
    for (int i = 0; i < 4; ++i) {
        int j = j0 + ty + 8 * i;
        const float* src = (j < 1024) ? (Wq + (size_t)j * 1024) : (Wk + (size_t)(j - 1024) * 1024);
        t[ty + 8 * i][tx] = src[d0 + tx];
    }
    __syncthreads();
#pragma unroll
    for (int i = 0; i < 4; ++i)
        WcatT[(size_t)(d0 + ty + 8 * i) * 2048 + j0 + tx] = t[tx][ty + 8 * i];
}

__global__ void k_thop(const float* __restrict__ Whop, float* __restrict__ WhopT) {
    __shared__ float t[32][33];
    int e0 = blockIdx.x * 32, d0 = blockIdx.y * 32;
    int tx = threadIdx.x, ty = threadIdx.y;
#pragma unroll
    for (int i = 0; i < 4; ++i)
        t[ty + 8 * i][tx] = Whop[(size_t)(d0 + ty + 8 * i) * 4096 + e0 + tx];
    __syncthreads();
#pragma unroll
    for (int i = 0; i < 4; ++i)
        WhopT[(size_t)(e0 + ty + 8 * i) * 1024 + d0 + tx] = t[tx][ty + 8 * i];
}

// ---------------- K1: Q/K projection (f32 SGEMM core, bf16 epilogue) ----------------
__global__ __launch_bounds__(256) void k_proj(const float* __restrict__ X,
                                              const float* __restrict__ Wq,
                                              const float* __restrict__ Wk,
                                              unsigned short* __restrict__ Qbg,
                                              unsigned short* __restrict__ Kbg) {
    __shared__ float As[128][20];
    __shared__ float Bs[128][20];
    const int tid = threadIdx.x;
    const int tx = tid & 15, ty = tid >> 4;
    const int rowBase = blockIdx.x * 128;
    const int byy = blockIdx.y;
    const float* Bsel = (byy < 8) ? Wq : Wk;
    unsigned short* Outb = (byy < 8) ? Qbg : Kbg;
    const int colBase = (byy & 7) * 128;

    float acc[8][8];
#pragma unroll
    for (int i = 0; i < 8; ++i)
#pragma unroll
        for (int j = 0; j < 8; ++j) acc[i][j] = 0.f;

    for (int kk = 0; kk < 1024; kk += 16) {
#pragma unroll
        for (int L = 0; L < 2; ++L) {
            int p = tid + L * 256;
            int row = p >> 2, c4 = p & 3;
            *(float4*)&As[row][c4 * 4] =
                *(const float4*)&X[(size_t)(rowBase + row) * 1024 + kk + c4 * 4];
            *(float4*)&Bs[row][c4 * 4] =
                *(const float4*)&Bsel[(size_t)(colBase + row) * 1024 + kk + c4 * 4];
        }
        __syncthreads();
#pragma unroll
        for (int k4 = 0; k4 < 4; ++k4) {
            float4 a[8], b[8];
#pragma unroll
            for (int i = 0; i < 8; ++i) a[i] = *(const float4*)&As[ty + 16 * i][k4 * 4];
#pragma unroll
            for (int j = 0; j < 8; ++j) b[j] = *(const float4*)&Bs[tx + 16 * j][k4 * 4];
#pragma unroll
            for (int i = 0; i < 8; ++i)
#pragma unroll
                for (int j = 0; j < 8; ++j)
                    acc[i][j] += a[i].x * b[j].x + a[i].y * b[j].y + a[i].z * b[j].z + a[i].w * b[j].w;
        }
        __syncthreads();
    }
#pragma unroll
    for (int i = 0; i < 8; ++i) {
        int rg = rowBase + ty + 16 * i;
        int b = rg >> 10, n = rg & 1023;
#pragma unroll
        for (int j = 0; j < 8; ++j) {
            int c = colBase + tx + 16 * j;
            int h = c >> 6, q = c & 63;
            Outb[((size_t)(b * 16 + h) * 1024 + n) * 64 + q] = f2b(acc[i][j]);
        }
    }
}

// ---------------- transpose Qb/Kb -> QT/KT (bf16) ----------------
__global__ __launch_bounds__(256) void k_tqk(const unsigned short* __restrict__ Qb,
                                             const unsigned short* __restrict__ Kb,
                                             unsigned short* __restrict__ QT,
                                             unsigned short* __restrict__ KT) {
    __shared__ unsigned short T[64][65];
    const int z = blockIdx.z;
    const unsigned short* src = z ? Kb : Qb;
    unsigned short* dst = z ? KT : QT;
    const int bh = blockIdx.y;
    const int n0 = blockIdx.x * 64;
    const int t = threadIdx.x;
    {
        int row = t >> 3;
        int colc = (t & 7) * 8;
#pragma unroll
        for (int ii = 0; ii < 2; ++ii) {
            int r = row + 32 * ii;
            v8u vv;
            vv.v = *(const short8v*)&src[((size_t)(bh << 10) + n0 + r) * 64 + colc];
#pragma unroll
            for (int j = 0; j < 8; ++j) T[r][colc + j] = vv.u[j];
        }
    }
    __syncthreads();
    {
        int q = t >> 2;
        int nc = (t & 3) * 16;
        unsigned short buf[16];
#pragma unroll
        for (int j = 0; j < 16; ++j) buf[j] = T[nc + j][q];
        *(short8v*)&dst[((size_t)bh * 64 + q) * 1024 + n0 + nc] = *(short8v*)&buf[0];
        *(short8v*)&dst[((size_t)bh * 64 + q) * 1024 + n0 + nc + 8] = *(short8v*)&buf[8];
    }
}

// ---------------- K2: row logsumexp via MFMA ----------------
// grid (64 bh, 8 n-tiles), 4 waves x 32 rows. No max-subtraction (scores bounded).
__global__ __launch_bounds__(256) void k_lse(const unsigned short* __restrict__ Qb,
                                             const unsigned short* __restrict__ Kb,
                                             float* __restrict__ LSE,
                                             float* __restrict__ PL) {
    const int tid = threadIdx.x, lane = tid & 63, wv = tid >> 6;
    const int bh = blockIdx.x, nt = blockIdx.y;
    const int nw = nt * 128 + wv * 32;
    const int lr = lane & 15, lg = lane >> 4;

    short8v qa[2][2];
#pragma unroll
    for (int rb = 0; rb < 2; ++rb)
#pragma unroll
        for (int kc = 0; kc < 2; ++kc)
            qa[rb][kc] = *(const short8v*)&Qb[((size_t)(bh << 10) + nw + rb * 16 + lr) * 64 + kc * 32 + lg * 8];

    float sm[2][4];
#pragma unroll
    for (int rb = 0; rb < 2; ++rb)
#pragma unroll
        for (int r = 0; r < 4; ++r) sm[rb][r] = 0.f;

    for (int mt = 0; mt < 64; ++mt) {
        const unsigned short* kp = &Kb[((size_t)(bh << 10) + mt * 16 + lr) * 64 + lg * 8];
        short8v bk0 = *(const short8v*)kp;
        short8v bk1 = *(const short8v*)(kp + 32);
#pragma unroll
        for (int rb = 0; rb < 2; ++rb) {
            f32x4 s = {0.f, 0.f, 0.f, 0.f};
            s = __builtin_amdgcn_mfma_f32_16x16x32_bf16(qa[rb][0], bk0, s, 0, 0, 0);
            s = __builtin_amdgcn_mfma_f32_16x16x32_bf16(qa[rb][1], bk1, s, 0, 0, 0);
#pragma unroll
            for (int r = 0; r < 4; ++r) sm[rb][r] += __expf(s[r] * BETA);
        }
    }
#pragma unroll
    for (int off = 1; off < 16; off <<= 1)
#pragma unroll
        for (int rb = 0; rb < 2; ++rb)
#pragma unroll
            for (int r = 0; r < 4; ++r) sm[rb][r] += __shfl_xor(sm[rb][r], off);

    float lsum = 0.f;
    if (lr == 0) {
#pragma unroll
        for (int rb = 0; rb < 2; ++rb)
#pragma unroll
            for (int r = 0; r < 4; ++r) {
                float l = __logf(sm[rb][r]);
                LSE[(size_t)(bh << 10) + nw + rb * 16 + lg * 4 + r] = l;
                lsum += l;
            }
    }
    lsum += __shfl_xor(lsum, 16);
    lsum += __shfl_xor(lsum, 32);
    if (lane == 0) PL[(size_t)(bh * 8 + nt) * 4 + wv] = lsum;
}

// ---------------- K3: dQ = -P K via MFMA ----------------
__global__ __launch_bounds__(256) void k_dq(const unsigned short* __restrict__ Qb,
                                            const unsigned short* __restrict__ Kb,
                                            const unsigned short* __restrict__ KT,
                                            const float* __restrict__ LSE,
                                            float* __restrict__ dQc) {
    __shared__ unsigned short P[4][2048];  // per-wave 32x64 bf16, XOR-swizzled
    const int tid = threadIdx.x, lane = tid & 63, wv = tid >> 6;
    const int bh = blockIdx.x, nt = blockIdx.y;
    const int nw = nt * 128 + wv * 32;
    const int lr = lane & 15, lg = lane >> 4;
    unsigned short* Pw = &P[wv][0];

    short8v qa[2][2];
#pragma unroll
    for (int rb = 0; rb < 2; ++rb)
#pragma unroll
        for (int kc = 0; kc < 2; ++kc)
            qa[rb][kc] = *(const short8v*)&Qb[((size_t)(bh << 10) + nw + rb * 16 + lr) * 64 + kc * 32 + lg * 8];

    float lse_r[2][4];
#pragma unroll
    for (int rb = 0; rb < 2; ++rb)
#pragma unroll
        for (int r = 0; r < 4; ++r)
            lse_r[rb][r] = LSE[(size_t)(bh << 10) + nw + rb * 16 + lg * 4 + r];

    f32x4 dq[2][4];
#pragma unroll
    for (int rb = 0; rb < 2; ++rb)
#pragma unroll
        for (int qb = 0; qb < 4; ++qb) dq[rb][qb] = (f32x4){0.f, 0.f, 0.f, 0.f};

    for (int mt = 0; mt < 16; ++mt) {
        const int m0 = mt * 64;
#pragma unroll
        for (int ct = 0; ct < 4; ++ct) {
            const unsigned short* kp = &Kb[((size_t)(bh << 10) + m0 + ct * 16 + lr) * 64 + lg * 8];
            short8v bk0 = *(const short8v*)kp;
            short8v bk1 = *(const short8v*)(kp + 32);
#pragma unroll
            for (int rb = 0; rb < 2; ++rb) {
                f32x4 s = {0.f, 0.f, 0.f, 0.f};
                s = __builtin_amdgcn_mfma_f32_16x16x32_bf16(qa[rb][0], bk0, s, 0, 0, 0);
                s = __builtin_amdgcn_mfma_f32_16x16x32_bf16(qa[rb][1], bk1, s, 0, 0, 0);
#pragma unroll
                for (int r = 0; r < 4; ++r) {
                    float p = __expf(s[r] * BETA - lse_r[rb][r]);
                    int row = rb * 16 + lg * 4 + r;
                    int off = (row * 64 + ct * 16 + lr) ^ ((row & 7) << 3);
                    Pw[off] = f2b(p);
                }
            }
        }
        short8v pa[2][2];
#pragma unroll
        for (int rb = 0; rb < 2; ++rb) {
            int row = rb * 16 + lr;
#pragma unroll
            for (int kc = 0; kc < 2; ++kc) {
                int off = (row * 64 + kc * 32 + lg * 8) ^ ((row & 7) << 3);
                pa[rb][kc] = *(const short8v*)&Pw[off];
            }
        }
#pragma unroll
        for (int qb = 0; qb < 4; ++qb) {
            const unsigned short* kp = &KT[((size_t)bh * 64 + qb * 16 + lr) * 1024 + m0 + lg * 8];
            short8v b0 = *(const short8v*)kp;
            short8v b1 = *(const short8v*)(kp + 32);
#pragma unroll
            for (int rb = 0; rb < 2; ++rb) {
                dq[rb][qb] = __builtin_amdgcn_mfma_f32_16x16x32_bf16(pa[rb][0], b0, dq[rb][qb], 0, 0, 0);
                dq[rb][qb] = __builtin_amdgcn_mfma_f32_16x16x32_bf16(pa[rb][1], b1, dq[rb][qb], 0, 0, 0);
            }
        }
    }
    const int b = bh >> 4, h = bh & 15;
#pragma unroll
    for (int rb = 0; rb < 2; ++rb)
#pragma unroll
        for (int qb = 0; qb < 4; ++qb)
#pragma unroll
            for (int r = 0; r < 4; ++r)
                dQc[((size_t)(b << 10) + nw + rb * 16 + lg * 4 + r) * 1024 + h * 64 + qb * 16 + lr] = -dq[rb][qb][r];
}

// ---------------- K4: dK = -P^T Q via MFMA (mirror of k_dq) ----------------
__global__ __launch_bounds__(256) void k_dk(const unsigned short* __restrict__ Qb,
                                            const unsigned short* __restrict__ Kb,
                                            const unsigned short* __restrict__ QT,
                                            const float* __restrict__ LSE,
                                            float* __restrict__ dKc) {
    __shared__ unsigned short P[4][2048];
    const int tid = threadIdx.x, lane = tid & 63, wv = tid >> 6;
    const int bh = blockIdx.x, mt = blockIdx.y;
    const int mw = mt * 128 + wv * 32;
    const int lr = lane & 15, lg = lane >> 4;
    unsigned short* Pw = &P[wv][0];

    short8v ka[2][2];
#pragma unroll
    for (int rb = 0; rb < 2; ++rb)
#pragma unroll
        for (int kc = 0; kc < 2; ++kc)
            ka[rb][kc] = *(const short8v*)&Kb[((size_t)(bh << 10) + mw + rb * 16 + lr) * 64 + kc * 32 + lg * 8];

    f32x4 dk[2][4];
#pragma unroll
    for (int rb = 0; rb < 2; ++rb)
#pragma unroll
        for (int qb = 0; qb < 4; ++qb) dk[rb][qb] = (f32x4){0.f, 0.f, 0.f, 0.f};

    for (int ntl = 0; ntl < 16; ++ntl) {
        const int n0 = ntl * 64;
#pragma unroll
        for (int ct = 0; ct < 4; ++ct) {
            const unsigned short* qp = &Qb[((size_t)(bh << 10) + n0 + ct * 16 + lr) * 64 + lg * 8];
            short8v bq0 = *(const short8v*)qp;
            short8v bq1 = *(const short8v*)(qp + 32);
            float lse_c = LSE[(size_t)(bh << 10) + n0 + ct * 16 + lr];
#pragma unroll
            for (int rb = 0; rb < 2; ++rb) {
                f32x4 s = {0.f, 0.f, 0.f, 0.f};
                s = __builtin_amdgcn_mfma_f32_16x16x32_bf16(ka[rb][0], bq0, s, 0, 0, 0);
                s = __builtin_amdgcn_mfma_f32_16x16x32_bf16(ka[rb][1], bq1, s, 0, 0, 0);
#pragma unroll
                for (int r = 0; r < 4; ++r) {
                    float p = __expf(s[r] * BETA - lse_c);
                    int row = rb * 16 + lg * 4 + r;
                    int off = (row * 64 + ct * 16 + lr) ^ ((row & 7) << 3);
                    Pw[off] = f2b(p);
                }
            }
        }
        short8v pa[2][2];
#pragma unroll
        for (int rb = 0; rb < 2; ++rb) {
            int row = rb * 16 + lr;
#pragma unroll
            for (int kc = 0; kc < 2; ++kc) {
                int off = (row * 64 + kc * 32 + lg * 8) ^ ((row & 7) << 3);
                pa[rb][kc] = *(const short8v*)&Pw[off];
            }
        }
#pragma unroll
        for (int qb = 0; qb < 4; ++qb) {
            const unsigned short* qp = &QT[((size_t)bh * 64 + qb * 16 + lr) * 1024 + n0 + lg * 8];
            short8v b0 = *(const short8v*)qp;
            short8v b1 = *(const short8v*)(qp + 32);
#pragma unroll
            for (int rb = 0; rb < 2; ++rb) {
                dk[rb][qb] = __builtin_amdgcn_mfma_f32_16x16x32_bf16(pa[rb][0], b0, dk[rb][qb], 0, 0, 0);
                dk[rb][qb] = __builtin_amdgcn_mfma_f32_16x16x32_bf16(pa[rb][1], b1, dk[rb][qb], 0, 0, 0);
            }
        }
    }
    const int b = bh >> 4, h = bh & 15;
#pragma unroll
    for (int rb = 0; rb < 2; ++rb)
#pragma unroll
        for (int qb = 0; qb < 4; ++qb)
#pragma unroll
            for (int r = 0; r < 4; ++r)
                dKc[((size_t)(b << 10) + mw + rb * 16 + lg * 4 + r) * 1024 + h * 64 + qb * 16 + lr] = -dk[rb][qb][r];
}

// ---------------- K6: Hopfield forward (f32 SGEMM, unchanged) ----------------
__global__ __launch_bounds__(256) void k_hopfwd(const float* __restrict__ X,
                                                const float* __restrict__ WhopT,
                                                __hip_bfloat16* __restrict__ Hm,
                                                float* __restrict__ partials) {
    __shared__ float As[128][20];
    __shared__ float Bs[128][20];
    __shared__ float red[4];
    const int tid = threadIdx.x;
    const int tx = tid & 15, ty = tid >> 4;
    const int rowBase = blockIdx.x * 128;
    const int colBase = blockIdx.y * 128;

    float acc[8][8];
#pragma unroll
    for (int i = 0; i < 8; ++i)
#pragma unroll
        for (int j = 0; j < 8; ++j) acc[i][j] = 0.f;

    for (int kk = 0; kk < 1024; kk += 16) {
#pragma unroll
        for (int L = 0; L < 2; ++L) {
            int p = tid + L * 256;
            int row = p >> 2, c4 = p & 3;
            *(float4*)&As[row][c4 * 4] =
                *(const float4*)&X[(size_t)(rowBase + row) * 1024 + kk + c4 * 4];
            *(float4*)&Bs[row][c4 * 4] =
                *(const float4*)&WhopT[(size_t)(colBase + row) * 1024 + kk + c4 * 4];
        }
        __syncthreads();
#pragma unroll
        for (int k4 = 0; k4 < 4; ++k4) {
            float4 a[8], b[8];
#pragma unroll
            for (int i = 0; i < 8; ++i) a[i] = *(const float4*)&As[ty + 16 * i][k4 * 4];
#pragma unroll
            for (int j = 0; j < 8; ++j) b[j] = *(const float4*)&Bs[tx + 16 * j][k4 * 4];
#pragma unroll
            for (int i = 0; i < 8; ++i)
#pragma unroll
                for (int j = 0; j < 8; ++j)
                    acc[i][j] += a[i].x * b[j].x + a[i].y * b[j].y + a[i].z * b[j].z + a[i].w * b[j].w;
        }
        __syncthreads();
    }
    float ss = 0.f;
#pragma unroll
    for (int i = 0; i < 8; ++i) {
        size_t r = rowBase + ty + 16 * i;
#pragma unroll
        for (int j = 0; j < 8; ++j) {
            float hv = fmaxf(acc[i][j], 0.f);
            ss += hv * hv;
            Hm[r * 4096 + colBase + tx + 16 * j] = __float2bfloat16(hv);
        }
    }
#pragma unroll
    for (int off = 32; off; off >>= 1) ss += __shfl_down(ss, off);
    if ((tid & 63) == 0) red[tid >> 6] = ss;
    __syncthreads();
    if (tid == 0) partials[blockIdx.y * gridDim.x + blockIdx.x] = red[0] + red[1] + red[2] + red[3];
}

// ---------------- K7: grad_hop = -H Whop^T ----------------
__global__ __launch_bounds__(256) void k_hopbwd(const unsigned short* __restrict__ Hm,
                                                const float* __restrict__ Whop,
                                                float* __restrict__ out) {
    __shared__ float As[128][20];
    __shared__ float Bs[128][20];
    const int tid = threadIdx.x;
    const int tx = tid & 15, ty = tid >> 4;
    const int rowBase = blockIdx.x * 128;
    const int colBase = blockIdx.y * 128;

    float acc[8][8];
#pragma unroll
    for (int i = 0; i < 8; ++i)
#pragma unroll
        for (int j = 0; j < 8; ++j) acc[i][j] = 0.f;

    for (int kk = 0; kk < 4096; kk += 16) {
#pragma unroll
        for (int L = 0; L < 2; ++L) {
            int p = tid + L * 256;
            int row = p >> 2, c4 = p & 3;
            ushort4 hv = *(const ushort4*)&Hm[(size_t)(rowBase + row) * 4096 + kk + c4 * 4];
            float4 af;
            af.x = __uint_as_float((unsigned)hv.x << 16);
            af.y = __uint_as_float((unsigned)hv.y << 16);
            af.z = __uint_as_float((unsigned)hv.z << 16);
            af.w = __uint_as_float((unsigned)hv.w << 16);
            *(float4*)&As[row][c4 * 4] = af;
            *(float4*)&Bs[row][c4 * 4] =
                *(const float4*)&Whop[(size_t)(colBase + row) * 4096 + kk + c4 * 4];
        }
        __syncthreads();
#pragma unroll
        for (int k4 = 0; k4 < 4; ++k4) {
            float4 a[8], b[8];
#pragma unroll
            for (int i = 0; i < 8; ++i) a[i] = *(const float4*)&As[ty + 16 * i][k4 * 4];
#pragma unroll
            for (int j = 0; j < 8; ++j) b[j] = *(const float4*)&Bs[tx + 16 * j][k4 * 4];
#pragma unroll
            for (int i = 0; i < 8; ++i)
#pragma unroll
                for (int j = 0; j < 8; ++j)
                    acc[i][j] += a[i].x * b[j].x + a[i].y * b[j].y + a[i].z * b[j].z + a[i].w * b[j].w;
        }
        __syncthreads();
    }
#pragma unroll
    for (int i = 0; i < 8; ++i) {
        size_t r = rowBase + ty + 16 * i;
#pragma unroll
        for (int j = 0; j < 8; ++j)
            out[r * 1024 + colBase + tx + 16 * j] = -acc[i][j];
    }
}

// ---------------- K5: out += dQ Wq + dK Wk ----------------
__global__ __launch_bounds__(256) void k_gradproj(const float* __restrict__ dQc,
                                                  const float* __restrict__ dKc,
                                                  const float* __restrict__ WcatT,
                                                  float* __restrict__ out) {
    __shared__ float As[128][20];
    __shared__ float Bs[128][20];
    const int tid = threadIdx.x;
    const int tx = tid & 15, ty = tid >> 4;
    const int rowBase = blockIdx.x * 128;
    const int colBase = blockIdx.y * 128;

    float acc[8][8];
#pragma unroll
    for (int i = 0; i < 8; ++i)
#pragma unroll
        for (int j = 0; j < 8; ++j) acc[i][j] = 0.f;

    for (int kk = 0; kk < 2048; kk += 16) {
        const float* Ap;
        int kloc;
        if (kk < 1024) { Ap = dQc; kloc = kk; } else { Ap = dKc; kloc = kk - 1024; }
#pragma unroll
        for (int L = 0; L < 2; ++L) {
            int p = tid + L * 256;
            int row = p >> 2, c4 = p & 3;
            *(float4*)&As[row][c4 * 4] =
                *(const float4*)&Ap[(size_t)(rowBase + row) * 1024 + kloc + c4 * 4];
            *(float4*)&Bs[row][c4 * 4] =
                *(const float4*)&WcatT[(size_t)(colBase + row) * 2048 + kk + c4 * 4];
        }
        __syncthreads();
#pragma unroll
        for (int k4 = 0; k4 < 4; ++k4) {
            float4 a[8], b[8];
#pragma unroll
            for (int i = 0; i < 8; ++i) a[i] = *(const float4*)&As[ty + 16 * i][k4 * 4];
#pragma unroll
            for (int j = 0; j < 8; ++j) b[j] = *(const float4*)&Bs[tx + 16 * j][k4 * 4];
#pragma unroll
            for (int i = 0; i < 8; ++i)
#pragma unroll
                for (int j = 0; j < 8; ++j)
                    acc[i][j] += a[i].x * b[j].x + a[i].y * b[j].y + a[i].z * b[j].z + a[i].w * b[j].w;
        }
        __syncthreads();
    }
#pragma unroll
    for (int i = 0; i < 8; ++i) {
        size_t r = rowBase + ty + 16 * i;
#pragma unroll
        for (int j = 0; j < 8; ++j) {
            size_t idx = r * 1024 + colBase + tx + 16 * j;
            out[idx] += acc[i][j];
        }
    }
}

// ---------------- K8: finalize energy ----------------
__global__ __launch_bounds__(256) void k_fin(const float* __restrict__ pl,
                                             const float* __restrict__ ph,
                                             float* __restrict__ out) {
    const int tid = threadIdx.x;
    float s1 = 0.f, s2 = 0.f;
    for (int i = tid; i < 2048; i += 256) s1 += pl[i];
    for (int i = tid; i < 1024; i += 256) s2 += ph[i];
#pragma unroll
    for (int off = 32; off; off >>= 1) {
        s1 += __shfl_down(s1, off);
        s2 += __shfl_down(s2, off);
    }
    __shared__ float r1[4], r2[4];
    if ((tid & 63) == 0) { r1[tid >> 6] = s1; r2[tid >> 6] = s2; }
    __syncthreads();
    if (tid == 0) {
        float S1 = r1[0] + r1[1] + r1[2] + r1[3];
        float S2 = r2[0] + r2[1] + r2[2] + r2[3];
        out[(size_t)4194304] = -INV_BETA * S1 - 0.5f * S2;
    }
}

extern "C" void kernel_launch(void* const* d_in, const int* in_sizes, int n_in,
                              void* d_out, int out_size, void* d_ws, size_t ws_size,
                              hipStream_t stream) {
    (void)in_sizes; (void)n_in; (void)out_size; (void)ws_size;
    const float* x    = (const float*)d_in[0];
    const float* Wq   = (const float*)d_in[1];
    const float* Wk   = (const float*)d_in[2];
    const float* Whop = (const float*)d_in[3];
    float* out = (float*)d_out;
    float* ws = (float*)d_ws;

    float* dQc   = ws + OFF_DQ;
    float* dKc   = ws + OFF_DK;
    float* WcatT = ws + OFF_WCT;
    float* WhopT = ws + OFF_WHT;
    __hip_bfloat16* Hm = (__hip_bfloat16*)(ws + OFF_H);
    unsigned short* Qb = (unsigned short*)(ws + OFF_QB);
    unsigned short* Kb = (unsigned short*)(ws + OFF_KB);
    unsigned short* QT = (unsigned short*)(ws + OFF_QT);
    unsigned short* KT = (unsigned short*)(ws + OFF_KT);
    float* LSE = ws + OFF_LSE;
    float* PL  = ws + OFF_PL;
    float* PH  = ws + OFF_PH;

    dim3 blk(256);
    k_tcat<<<dim3(64, 32), dim3(32, 8), 0, stream>>>(Wq, Wk, WcatT);
    k_thop<<<dim3(128, 32), dim3(32, 8), 0, stream>>>(Whop, WhopT);
    k_proj<<<dim3(32, 16), blk, 0, stream>>>(x, Wq, Wk, Qb, Kb);
    k_tqk<<<dim3(16, 64, 2), blk, 0, stream>>>(Qb, Kb, QT, KT);
    k_lse<<<dim3(64, 8), blk, 0, stream>>>(Qb, Kb, LSE, PL);
    k_dq<<<dim3(64, 8), blk, 0, stream>>>(Qb, Kb, KT, LSE, dQc);
    k_dk<<<dim3(64, 8), blk, 0, stream>>>(Qb, Kb, QT, LSE, dKc);
    k_hopfwd<<<dim3(32, 32), blk, 0, stream>>>(x, WhopT, Hm, PH);
    k_hopbwd<<<dim3(32, 8), blk, 0, stream>>>((const unsigned short*)Hm, Whop, out);
    k_gradproj<<<dim3(32, 8), blk, 0, stream>>>(dQc, dKc, WcatT, out);
    k_fin<<<dim3(1), blk, 0, stream>>>(PL, PH, out);
}

// Round 4
// 660.241 us; speedup vs baseline: 9.8995x; 3.7924x over previous
//
#include <hip/hip_runtime.h>
#include <hip/hip_bf16.h>
#include <math.h>

#define BETA 0.125f
#define INV_BETA 8.0f

typedef __attribute__((ext_vector_type(8))) short short8v;
typedef __attribute__((ext_vector_type(4))) float f32x4;
typedef union { short8v v; unsigned short u[8]; } v8u;

// ws layout (float units)
#define OFF_XB   0u          // bf16 x      [4096][1024]
#define OFF_WCB  2097152u    // bf16 Wcat   [2048][1024] (rows j=(h,q) for Wq then Wk)
#define OFF_WCTB 3145728u    // bf16 WcatT  [1024][2048]
#define OFF_WHB  4194304u    // bf16 Whop   [1024][4096]
#define OFF_WHTB 6291456u    // bf16 WhopT  [4096][1024]
#define OFF_H    8388608u    // bf16 H      [4096][4096]
#define OFF_QB   16777216u   // bf16 Qb     [64][1024][64]
#define OFF_KB   18874368u   // bf16 Kb
#define OFF_QT   20971520u   // bf16 QT     [64][64][1024]
#define OFF_KT   23068672u   // bf16 KT
#define OFF_DQK  25165824u   // bf16 dQKcat [4096][2048]
#define OFF_LSE  29360128u   // f32 [65536]
#define OFF_PL   29425664u   // f32 [2048]
#define OFF_PH   29427712u   // f32 [1024]

__device__ __forceinline__ unsigned short f2b(float f) {
    unsigned u = __float_as_uint(f);
    return (unsigned short)((u + 0x7fffu + ((u >> 16) & 1u)) >> 16);
}

// ---------------- bf16 cast (float4 -> ushort4) ----------------
__global__ __launch_bounds__(256) void k_cast(const float* __restrict__ src,
                                              unsigned short* __restrict__ dst, int n4) {
    int i = blockIdx.x * 256 + threadIdx.x;
    if (i < n4) {
        float4 v = ((const float4*)src)[i];
        ushort4 o;
        o.x = f2b(v.x); o.y = f2b(v.y); o.z = f2b(v.z); o.w = f2b(v.w);
        ((ushort4*)dst)[i] = o;
    }
}

// ---------------- bf16 transposes ----------------
__global__ void k_tcatb(const float* __restrict__ Wq, const float* __restrict__ Wk,
                        unsigned short* __restrict__ WCTB) {
    __shared__ float t[32][33];
    int j0 = blockIdx.x * 32, d0 = blockIdx.y * 32;
    int tx = threadIdx.x, ty = threadIdx.y;
#pragma unroll
    for (int i = 0; i < 4; ++i) {
        int j = j0 + ty + 8 * i;
        const float* src = (j < 1024) ? (Wq + (size_t)j * 1024) : (Wk + (size_t)(j - 1024) * 1024);
        t[ty + 8 * i][tx] = src[d0 + tx];
    }
    __syncthreads();
#pragma unroll
    for (int i = 0; i < 4; ++i)
        WCTB[(size_t)(d0 + ty + 8 * i) * 2048 + j0 + tx] = f2b(t[tx][ty + 8 * i]);
}

__global__ void k_thopb(const float* __restrict__ Whop, unsigned short* __restrict__ WHTB) {
    __shared__ float t[32][33];
    int e0 = blockIdx.x * 32, d0 = blockIdx.y * 32;
    int tx = threadIdx.x, ty = threadIdx.y;
#pragma unroll
    for (int i = 0; i < 4; ++i)
        t[ty + 8 * i][tx] = Whop[(size_t)(d0 + ty + 8 * i) * 4096 + e0 + tx];
    __syncthreads();
#pragma unroll
    for (int i = 0; i < 4; ++i)
        WHTB[(size_t)(e0 + ty + 8 * i) * 1024 + d0 + tx] = f2b(t[tx][ty + 8 * i]);
}

// ============ generic MFMA NT tile body (A rows [M][K], B rows [N][K]) ============
// 128x128 block tile, 4 waves (2x2), 64x64 per wave, K-step 32.
#define MM_PROLOG(KDIM)                                                          \
    const int tid = threadIdx.x, lane = tid & 63, wv = tid >> 6;                 \
    const int lr = lane & 15, lg = lane >> 4;                                    \
    const int row0 = blockIdx.x * 128 + (wv >> 1) * 64;                          \
    const int col0 = blockIdx.y * 128 + (wv & 1) * 64;                           \
    f32x4 acc[4][4];                                                             \
    _Pragma("unroll") for (int i = 0; i < 4; ++i)                                \
        _Pragma("unroll") for (int j = 0; j < 4; ++j)                            \
            acc[i][j] = (f32x4){0.f, 0.f, 0.f, 0.f};

#define MM_KLOOP(Aptr, ALD, Bptr, BLD, KDIM)                                     \
    _Pragma("unroll 2") for (int kk = 0; kk < (KDIM); kk += 32) {                \
        short8v a[4], b[4];                                                      \
        _Pragma("unroll") for (int i = 0; i < 4; ++i)                            \
            a[i] = *(const short8v*)&(Aptr)[(size_t)(row0 + i * 16 + lr) * (ALD) + kk + lg * 8]; \
        _Pragma("unroll") for (int j = 0; j < 4; ++j)                            \
            b[j] = *(const short8v*)&(Bptr)[(size_t)(col0 + j * 16 + lr) * (BLD) + kk + lg * 8]; \
        _Pragma("unroll") for (int i = 0; i < 4; ++i)                            \
            _Pragma("unroll") for (int j = 0; j < 4; ++j)                        \
                acc[i][j] = __builtin_amdgcn_mfma_f32_16x16x32_bf16(a[i], b[j], acc[i][j], 0, 0, 0); \
    }

// ---------------- K1: Q/K projection ----------------
// C[n_g][j] = sum_d x[n_g][d] * Wcat[j][d]; epilogue scatters bf16 into Qb/Kb layout.
__global__ __launch_bounds__(256) void mm_proj(const unsigned short* __restrict__ XB,
                                               const unsigned short* __restrict__ WCB,
                                               unsigned short* __restrict__ Qb,
                                               unsigned short* __restrict__ Kb) {
    MM_PROLOG(1024)
    MM_KLOOP(XB, 1024, WCB, 1024, 1024)
    unsigned short* dst = (col0 < 1024) ? Qb : Kb;
    const int cbase = col0 & 1023;
#pragma unroll
    for (int i = 0; i < 4; ++i)
#pragma unroll
        for (int r = 0; r < 4; ++r) {
            int rg = row0 + i * 16 + lg * 4 + r;
            int bb = rg >> 10, n = rg & 1023;
#pragma unroll
            for (int j = 0; j < 4; ++j) {
                int c = cbase + j * 16 + lr;
                int h = c >> 6, q = c & 63;
                dst[((size_t)(bb * 16 + h) * 1024 + n) * 64 + q] = f2b(acc[i][j][r]);
            }
        }
}

// ---------------- K6: H = relu(x Whop), e_hop partials ----------------
__global__ __launch_bounds__(256) void mm_hopfwd(const unsigned short* __restrict__ XB,
                                                 const unsigned short* __restrict__ WHTB,
                                                 unsigned short* __restrict__ H,
                                                 float* __restrict__ PH) {
    __shared__ float red[4];
    MM_PROLOG(1024)
    MM_KLOOP(XB, 1024, WHTB, 1024, 1024)
    float ss = 0.f;
#pragma unroll
    for (int i = 0; i < 4; ++i)
#pragma unroll
        for (int r = 0; r < 4; ++r) {
            size_t rg = row0 + i * 16 + lg * 4 + r;
#pragma unroll
            for (int j = 0; j < 4; ++j) {
                float hv = fmaxf(acc[i][j][r], 0.f);
                ss += hv * hv;
                H[rg * 4096 + col0 + j * 16 + lr] = f2b(hv);
            }
        }
#pragma unroll
    for (int off = 32; off; off >>= 1) ss += __shfl_down(ss, off);
    if (lane == 0) red[wv] = ss;
    __syncthreads();
    if (tid == 0) PH[blockIdx.y * gridDim.x + blockIdx.x] = red[0] + red[1] + red[2] + red[3];
}

// ---------------- K7: out = -(H Whop^T) ----------------
__global__ __launch_bounds__(256) void mm_hopbwd(const unsigned short* __restrict__ H,
                                                 const unsigned short* __restrict__ WHB,
                                                 float* __restrict__ out) {
    MM_PROLOG(4096)
    MM_KLOOP(H, 4096, WHB, 4096, 4096)
#pragma unroll
    for (int i = 0; i < 4; ++i)
#pragma unroll
        for (int r = 0; r < 4; ++r) {
            size_t rg = row0 + i * 16 + lg * 4 + r;
#pragma unroll
            for (int j = 0; j < 4; ++j)
                out[rg * 1024 + col0 + j * 16 + lr] = -acc[i][j][r];
        }
}

// ---------------- K5: out += dQKcat x WcatT ----------------
__global__ __launch_bounds__(256) void mm_gradproj(const unsigned short* __restrict__ DQK,
                                                   const unsigned short* __restrict__ WCTB,
                                                   float* __restrict__ out) {
    MM_PROLOG(2048)
    MM_KLOOP(DQK, 2048, WCTB, 2048, 2048)
#pragma unroll
    for (int i = 0; i < 4; ++i)
#pragma unroll
        for (int r = 0; r < 4; ++r) {
            size_t rg = row0 + i * 16 + lg * 4 + r;
#pragma unroll
            for (int j = 0; j < 4; ++j) {
                size_t idx = rg * 1024 + col0 + j * 16 + lr;
                out[idx] += acc[i][j][r];
            }
        }
}

// ---------------- transpose Qb/Kb -> QT/KT (bf16) ----------------
__global__ __launch_bounds__(256) void k_tqk(const unsigned short* __restrict__ Qb,
                                             const unsigned short* __restrict__ Kb,
                                             unsigned short* __restrict__ QT,
                                             unsigned short* __restrict__ KT) {
    __shared__ unsigned short T[64][65];
    const int z = blockIdx.z;
    const unsigned short* src = z ? Kb : Qb;
    unsigned short* dst = z ? KT : QT;
    const int bh = blockIdx.y;
    const int n0 = blockIdx.x * 64;
    const int t = threadIdx.x;
    {
        int row = t >> 3;
        int colc = (t & 7) * 8;
#pragma unroll
        for (int ii = 0; ii < 2; ++ii) {
            int r = row + 32 * ii;
            v8u vv;
            vv.v = *(const short8v*)&src[((size_t)(bh << 10) + n0 + r) * 64 + colc];
#pragma unroll
            for (int j = 0; j < 8; ++j) T[r][colc + j] = vv.u[j];
        }
    }
    __syncthreads();
    {
        int q = t >> 2;
        int nc = (t & 3) * 16;
        unsigned short buf[16];
#pragma unroll
        for (int j = 0; j < 16; ++j) buf[j] = T[nc + j][q];
        *(short8v*)&dst[((size_t)bh * 64 + q) * 1024 + n0 + nc] = *(short8v*)&buf[0];
        *(short8v*)&dst[((size_t)bh * 64 + q) * 1024 + n0 + nc + 8] = *(short8v*)&buf[8];
    }
}

// ---------------- K2: row logsumexp via MFMA ----------------
__global__ __launch_bounds__(256) void k_lse(const unsigned short* __restrict__ Qb,
                                             const unsigned short* __restrict__ Kb,
                                             float* __restrict__ LSE,
                                             float* __restrict__ PL) {
    const int tid = threadIdx.x, lane = tid & 63, wv = tid >> 6;
    const int bh = blockIdx.x, nt = blockIdx.y;
    const int nw = nt * 128 + wv * 32;
    const int lr = lane & 15, lg = lane >> 4;

    short8v qa[2][2];
#pragma unroll
    for (int rb = 0; rb < 2; ++rb)
#pragma unroll
        for (int kc = 0; kc < 2; ++kc)
            qa[rb][kc] = *(const short8v*)&Qb[((size_t)(bh << 10) + nw + rb * 16 + lr) * 64 + kc * 32 + lg * 8];

    float sm[2][4];
#pragma unroll
    for (int rb = 0; rb < 2; ++rb)
#pragma unroll
        for (int r = 0; r < 4; ++r) sm[rb][r] = 0.f;

    for (int mt = 0; mt < 64; ++mt) {
        const unsigned short* kp = &Kb[((size_t)(bh << 10) + mt * 16 + lr) * 64 + lg * 8];
        short8v bk0 = *(const short8v*)kp;
        short8v bk1 = *(const short8v*)(kp + 32);
#pragma unroll
        for (int rb = 0; rb < 2; ++rb) {
            f32x4 s = {0.f, 0.f, 0.f, 0.f};
            s = __builtin_amdgcn_mfma_f32_16x16x32_bf16(qa[rb][0], bk0, s, 0, 0, 0);
            s = __builtin_amdgcn_mfma_f32_16x16x32_bf16(qa[rb][1], bk1, s, 0, 0, 0);
#pragma unroll
            for (int r = 0; r < 4; ++r) sm[rb][r] += __expf(s[r] * BETA);
        }
    }
#pragma unroll
    for (int off = 1; off < 16; off <<= 1)
#pragma unroll
        for (int rb = 0; rb < 2; ++rb)
#pragma unroll
            for (int r = 0; r < 4; ++r) sm[rb][r] += __shfl_xor(sm[rb][r], off);

    float lsum = 0.f;
    if (lr == 0) {
#pragma unroll
        for (int rb = 0; rb < 2; ++rb)
#pragma unroll
            for (int r = 0; r < 4; ++r) {
                float l = __logf(sm[rb][r]);
                LSE[(size_t)(bh << 10) + nw + rb * 16 + lg * 4 + r] = l;
                lsum += l;
            }
    }
    lsum += __shfl_xor(lsum, 16);
    lsum += __shfl_xor(lsum, 32);
    if (lane == 0) PL[(size_t)(bh * 8 + nt) * 4 + wv] = lsum;
}

// ---------------- K3: dQ = -P K -> DQK bf16 cols 0..1023 ----------------
__global__ __launch_bounds__(256) void k_dq(const unsigned short* __restrict__ Qb,
                                            const unsigned short* __restrict__ Kb,
                                            const unsigned short* __restrict__ KT,
                                            const float* __restrict__ LSE,
                                            unsigned short* __restrict__ DQK) {
    __shared__ unsigned short P[4][2048];
    const int tid = threadIdx.x, lane = tid & 63, wv = tid >> 6;
    const int bh = blockIdx.x, nt = blockIdx.y;
    const int nw = nt * 128 + wv * 32;
    const int lr = lane & 15, lg = lane >> 4;
    unsigned short* Pw = &P[wv][0];

    short8v qa[2][2];
#pragma unroll
    for (int rb = 0; rb < 2; ++rb)
#pragma unroll
        for (int kc = 0; kc < 2; ++kc)
            qa[rb][kc] = *(const short8v*)&Qb[((size_t)(bh << 10) + nw + rb * 16 + lr) * 64 + kc * 32 + lg * 8];

    float lse_r[2][4];
#pragma unroll
    for (int rb = 0; rb < 2; ++rb)
#pragma unroll
        for (int r = 0; r < 4; ++r)
            lse_r[rb][r] = LSE[(size_t)(bh << 10) + nw + rb * 16 + lg * 4 + r];

    f32x4 dq[2][4];
#pragma unroll
    for (int rb = 0; rb < 2; ++rb)
#pragma unroll
        for (int qb = 0; qb < 4; ++qb) dq[rb][qb] = (f32x4){0.f, 0.f, 0.f, 0.f};

    for (int mt = 0; mt < 16; ++mt) {
        const int m0 = mt * 64;
#pragma unroll
        for (int ct = 0; ct < 4; ++ct) {
            const unsigned short* kp = &Kb[((size_t)(bh << 10) + m0 + ct * 16 + lr) * 64 + lg * 8];
            short8v bk0 = *(const short8v*)kp;
            short8v bk1 = *(const short8v*)(kp + 32);
#pragma unroll
            for (int rb = 0; rb < 2; ++rb) {
                f32x4 s = {0.f, 0.f, 0.f, 0.f};
                s = __builtin_amdgcn_mfma_f32_16x16x32_bf16(qa[rb][0], bk0, s, 0, 0, 0);
                s = __builtin_amdgcn_mfma_f32_16x16x32_bf16(qa[rb][1], bk1, s, 0, 0, 0);
#pragma unroll
                for (int r = 0; r < 4; ++r) {
                    float p = __expf(s[r] * BETA - lse_r[rb][r]);
                    int row = rb * 16 + lg * 4 + r;
                    int off = (row * 64 + ct * 16 + lr) ^ ((row & 7) << 3);
                    Pw[off] = f2b(p);
                }
            }
        }
        short8v pa[2][2];
#pragma unroll
        for (int rb = 0; rb < 2; ++rb) {
            int row = rb * 16 + lr;
#pragma unroll
            for (int kc = 0; kc < 2; ++kc) {
                int off = (row * 64 + kc * 32 + lg * 8) ^ ((row & 7) << 3);
                pa[rb][kc] = *(const short8v*)&Pw[off];
            }
        }
#pragma unroll
        for (int qb = 0; qb < 4; ++qb) {
            const unsigned short* kp = &KT[((size_t)bh * 64 + qb * 16 + lr) * 1024 + m0 + lg * 8];
            short8v b0 = *(const short8v*)kp;
            short8v b1 = *(const short8v*)(kp + 32);
#pragma unroll
            for (int rb = 0; rb < 2; ++rb) {
                dq[rb][qb] = __builtin_amdgcn_mfma_f32_16x16x32_bf16(pa[rb][0], b0, dq[rb][qb], 0, 0, 0);
                dq[rb][qb] = __builtin_amdgcn_mfma_f32_16x16x32_bf16(pa[rb][1], b1, dq[rb][qb], 0, 0, 0);
            }
        }
    }
    const int b = bh >> 4, h = bh & 15;
#pragma unroll
    for (int rb = 0; rb < 2; ++rb)
#pragma unroll
        for (int qb = 0; qb < 4; ++qb)
#pragma unroll
            for (int r = 0; r < 4; ++r)
                DQK[((size_t)(b << 10) + nw + rb * 16 + lg * 4 + r) * 2048 + h * 64 + qb * 16 + lr] = f2b(-dq[rb][qb][r]);
}

// ---------------- K4: dK = -P^T Q -> DQK bf16 cols 1024..2047 ----------------
__global__ __launch_bounds__(256) void k_dk(const unsigned short* __restrict__ Qb,
                                            const unsigned short* __restrict__ Kb,
                                            const unsigned short* __restrict__ QT,
                                            const float* __restrict__ LSE,
                                            unsigned short* __restrict__ DQK) {
    __shared__ unsigned short P[4][2048];
    const int tid = threadIdx.x, lane = tid & 63, wv = tid >> 6;
    const int bh = blockIdx.x, mt = blockIdx.y;
    const int mw = mt * 128 + wv * 32;
    const int lr = lane & 15, lg = lane >> 4;
    unsigned short* Pw = &P[wv][0];

    short8v ka[2][2];
#pragma unroll
    for (int rb = 0; rb < 2; ++rb)
#pragma unroll
        for (int kc = 0; kc < 2; ++kc)
            ka[rb][kc] = *(const short8v*)&Kb[((size_t)(bh << 10) + mw + rb * 16 + lr) * 64 + kc * 32 + lg * 8];

    f32x4 dk[2][4];
#pragma unroll
    for (int rb = 0; rb < 2; ++rb)
#pragma unroll
        for (int qb = 0; qb < 4; ++qb) dk[rb][qb] = (f32x4){0.f, 0.f, 0.f, 0.f};

    for (int ntl = 0; ntl < 16; ++ntl) {
        const int n0 = ntl * 64;
#pragma unroll
        for (int ct = 0; ct < 4; ++ct) {
            const unsigned short* qp = &Qb[((size_t)(bh << 10) + n0 + ct * 16 + lr) * 64 + lg * 8];
            short8v bq0 = *(const short8v*)qp;
            short8v bq1 = *(const short8v*)(qp + 32);
            float lse_c = LSE[(size_t)(bh << 10) + n0 + ct * 16 + lr];
#pragma unroll
            for (int rb = 0; rb < 2; ++rb) {
                f32x4 s = {0.f, 0.f, 0.f, 0.f};
                s = __builtin_amdgcn_mfma_f32_16x16x32_bf16(ka[rb][0], bq0, s, 0, 0, 0);
                s = __builtin_amdgcn_mfma_f32_16x16x32_bf16(ka[rb][1], bq1, s, 0, 0, 0);
#pragma unroll
                for (int r = 0; r < 4; ++r) {
                    float p = __expf(s[r] * BETA - lse_c);
                    int row = rb * 16 + lg * 4 + r;
                    int off = (row * 64 + ct * 16 + lr) ^ ((row & 7) << 3);
                    Pw[off] = f2b(p);
                }
            }
        }
        short8v pa[2][2];
#pragma unroll
        for (int rb = 0; rb < 2; ++rb) {
            int row = rb * 16 + lr;
#pragma unroll
            for (int kc = 0; kc < 2; ++kc) {
                int off = (row * 64 + kc * 32 + lg * 8) ^ ((row & 7) << 3);
                pa[rb][kc] = *(const short8v*)&Pw[off];
            }
        }
#pragma unroll
        for (int qb = 0; qb < 4; ++qb) {
            const unsigned short* qp = &QT[((size_t)bh * 64 + qb * 16 + lr) * 1024 + n0 + lg * 8];
            short8v b0 = *(const short8v*)qp;
            short8v b1 = *(const short8v*)(qp + 32);
#pragma unroll
            for (int rb = 0; rb < 2; ++rb) {
                dk[rb][qb] = __builtin_amdgcn_mfma_f32_16x16x32_bf16(pa[rb][0], b0, dk[rb][qb], 0, 0, 0);
                dk[rb][qb] = __builtin_amdgcn_mfma_f32_16x16x32_bf16(pa[rb][1], b1, dk[rb][qb], 0, 0, 0);
            }
        }
    }
    const int b = bh >> 4, h = bh & 15;
#pragma unroll
    for (int rb = 0; rb < 2; ++rb)
#pragma unroll
        for (int qb = 0; qb < 4; ++qb)
#pragma unroll
            for (int r = 0; r < 4; ++r)
                DQK[((size_t)(b << 10) + mw + rb * 16 + lg * 4 + r) * 2048 + 1024 + h * 64 + qb * 16 + lr] = f2b(-dk[rb][qb][r]);
}

// ---------------- K8: finalize energy ----------------
__global__ __launch_bounds__(256) void k_fin(const float* __restrict__ pl,
                                             const float* __restrict__ ph,
                                             float* __restrict__ out) {
    const int tid = threadIdx.x;
    float s1 = 0.f, s2 = 0.f;
    for (int i = tid; i < 2048; i += 256) s1 += pl[i];
    for (int i = tid; i < 1024; i += 256) s2 += ph[i];
#pragma unroll
    for (int off = 32; off; off >>= 1) {
        s1 += __shfl_down(s1, off);
        s2 += __shfl_down(s2, off);
    }
    __shared__ float r1[4], r2[4];
    if ((tid & 63) == 0) { r1[tid >> 6] = s1; r2[tid >> 6] = s2; }
    __syncthreads();
    if (tid == 0) {
        float S1 = r1[0] + r1[1] + r1[2] + r1[3];
        float S2 = r2[0] + r2[1] + r2[2] + r2[3];
        out[(size_t)4194304] = -INV_BETA * S1 - 0.5f * S2;
    }
}

extern "C" void kernel_launch(void* const* d_in, const int* in_sizes, int n_in,
                              void* d_out, int out_size, void* d_ws, size_t ws_size,
                              hipStream_t stream) {
    (void)in_sizes; (void)n_in; (void)out_size; (void)ws_size;
    const float* x    = (const float*)d_in[0];
    const float* Wq   = (const float*)d_in[1];
    const float* Wk   = (const float*)d_in[2];
    const float* Whop = (const float*)d_in[3];
    float* out = (float*)d_out;
    float* ws = (float*)d_ws;

    unsigned short* XB   = (unsigned short*)(ws + OFF_XB);
    unsigned short* WCB  = (unsigned short*)(ws + OFF_WCB);
    unsigned short* WCTB = (unsigned short*)(ws + OFF_WCTB);
    unsigned short* WHB  = (unsigned short*)(ws + OFF_WHB);
    unsigned short* WHTB = (unsigned short*)(ws + OFF_WHTB);
    unsigned short* H    = (unsigned short*)(ws + OFF_H);
    unsigned short* Qb   = (unsigned short*)(ws + OFF_QB);
    unsigned short* Kb   = (unsigned short*)(ws + OFF_KB);
    unsigned short* QT   = (unsigned short*)(ws + OFF_QT);
    unsigned short* KT   = (unsigned short*)(ws + OFF_KT);
    unsigned short* DQK  = (unsigned short*)(ws + OFF_DQK);
    float* LSE = ws + OFF_LSE;
    float* PL  = ws + OFF_PL;
    float* PH  = ws + OFF_PH;

    dim3 blk(256);
    k_cast<<<dim3(4096), blk, 0, stream>>>(x, XB, 1048576);
    k_cast<<<dim3(1024), blk, 0, stream>>>(Wq, WCB, 262144);
    k_cast<<<dim3(1024), blk, 0, stream>>>(Wk, WCB + 1048576, 262144);
    k_cast<<<dim3(4096), blk, 0, stream>>>(Whop, WHB, 1048576);
    k_tcatb<<<dim3(64, 32), dim3(32, 8), 0, stream>>>(Wq, Wk, WCTB);
    k_thopb<<<dim3(128, 32), dim3(32, 8), 0, stream>>>(Whop, WHTB);

    mm_proj<<<dim3(32, 16), blk, 0, stream>>>(XB, WCB, Qb, Kb);
    k_tqk<<<dim3(16, 64, 2), blk, 0, stream>>>(Qb, Kb, QT, KT);
    k_lse<<<dim3(64, 8), blk, 0, stream>>>(Qb, Kb, LSE, PL);
    k_dq<<<dim3(64, 8), blk, 0, stream>>>(Qb, Kb, KT, LSE, DQK);
    k_dk<<<dim3(64, 8), blk, 0, stream>>>(Qb, Kb, QT, LSE, DQK);

    mm_hopfwd<<<dim3(32, 32), blk, 0, stream>>>(XB, WHTB, H, PH);
    mm_hopbwd<<<dim3(32, 8), blk, 0, stream>>>(H, WHB, out);
    mm_gradproj<<<dim3(32, 8), blk, 0, stream>>>(DQK, WCTB, out);
    k_fin<<<dim3(1), blk, 0, stream>>>(PL, PH, out);
}

// Round 5
// 417.230 us; speedup vs baseline: 15.6654x; 1.5824x over previous
//
#include <hip/hip_runtime.h>
#include <hip/hip_bf16.h>
#include <math.h>

#define BETA 0.125f
#define INV_BETA 8.0f

typedef __attribute__((ext_vector_type(8))) short short8v;
typedef __attribute__((ext_vector_type(4))) float f32x4;
typedef union { short8v v; unsigned short u[8]; } v8u;

// ws layout (float units)
#define OFF_XB   0u          // bf16 x      [4096][1024]
#define OFF_WCB  2097152u    // bf16 Wcat   [2048][1024]
#define OFF_WCTB 3145728u    // bf16 WcatT  [1024][2048]
#define OFF_WHB  4194304u    // bf16 Whop   [1024][4096]
#define OFF_WHTB 6291456u    // bf16 WhopT  [4096][1024]
#define OFF_H    8388608u    // bf16 H      [4096][4096]
#define OFF_QB   16777216u   // bf16 Qb     [64][1024][64]
#define OFF_KB   18874368u   // bf16 Kb
#define OFF_QT   20971520u   // bf16 QT     [64][64][1024]
#define OFF_KT   23068672u   // bf16 KT
#define OFF_DQK  25165824u   // bf16 dQKcat [4096][2048]
#define OFF_LSE  29360128u   // f32 [65536]
#define OFF_PL   29425664u   // f32 [2048]
#define OFF_PH   29427712u   // f32 [1024]

__device__ __forceinline__ unsigned short f2b(float f) {
    unsigned u = __float_as_uint(f);
    return (unsigned short)((u + 0x7fffu + ((u >> 16) & 1u)) >> 16);
}

__device__ __forceinline__ void gload_lds16(const unsigned short* g, void* l) {
    __builtin_amdgcn_global_load_lds(
        (const __attribute__((address_space(1))) unsigned int*)g,
        (__attribute__((address_space(3))) unsigned int*)l, 16, 0, 0);
}

// ---------------- bf16 cast ----------------
__global__ __launch_bounds__(256) void k_cast(const float* __restrict__ src,
                                              unsigned short* __restrict__ dst, int n4) {
    int i = blockIdx.x * 256 + threadIdx.x;
    if (i < n4) {
        float4 v = ((const float4*)src)[i];
        ushort4 o;
        o.x = f2b(v.x); o.y = f2b(v.y); o.z = f2b(v.z); o.w = f2b(v.w);
        ((ushort4*)dst)[i] = o;
    }
}

// ---------------- bf16 transposes ----------------
__global__ void k_tcatb(const float* __restrict__ Wq, const float* __restrict__ Wk,
                        unsigned short* __restrict__ WCTB) {
    __shared__ float t[32][33];
    int j0 = blockIdx.x * 32, d0 = blockIdx.y * 32;
    int tx = threadIdx.x, ty = threadIdx.y;
#pragma unroll
    for (int i = 0; i < 4; ++i) {
        int j = j0 + ty + 8 * i;
        const float* src = (j < 1024) ? (Wq + (size_t)j * 1024) : (Wk + (size_t)(j - 1024) * 1024);
        t[ty + 8 * i][tx] = src[d0 + tx];
    }
    __syncthreads();
#pragma unroll
    for (int i = 0; i < 4; ++i)
        WCTB[(size_t)(d0 + ty + 8 * i) * 2048 + j0 + tx] = f2b(t[tx][ty + 8 * i]);
}

__global__ void k_thopb(const float* __restrict__ Whop, unsigned short* __restrict__ WHTB) {
    __shared__ float t[32][33];
    int e0 = blockIdx.x * 32, d0 = blockIdx.y * 32;
    int tx = threadIdx.x, ty = threadIdx.y;
#pragma unroll
    for (int i = 0; i < 4; ++i)
        t[ty + 8 * i][tx] = Whop[(size_t)(d0 + ty + 8 * i) * 4096 + e0 + tx];
    __syncthreads();
#pragma unroll
    for (int i = 0; i < 4; ++i)
        WHTB[(size_t)(e0 + ty + 8 * i) * 1024 + d0 + tx] = f2b(t[tx][ty + 8 * i]);
}

// ============ m97-structure GEMM core (NT: A[M][K] x B[N][K]) ============
// BM=128, BK=64, 4 waves (2x2). NJ=4 -> BN=128 (64x64/wave); NJ=2 -> BN=64 (64x32/wave).
// LDS linear dest for global_load_lds; XOR swizzle (chunk ^= row&7) applied on the
// GLOBAL SOURCE (staging) and on the ds_read address (rule #21 involution pair).
template <int NJ>
__device__ __forceinline__ void gemm_core(const unsigned short* __restrict__ A, int lda,
                                          const unsigned short* __restrict__ Bm, int ldb,
                                          int kdim, int rowBase, int colBase,
                                          unsigned short* ldsA, unsigned short* ldsB,
                                          f32x4 (&acc)[4][NJ]) {
    const int tid = threadIdx.x, lane = tid & 63;
    const int wv = tid >> 6;
    const int lr = lane & 15, lg = lane >> 4;
    const int wrow = (wv >> 1) * 64;
    const int wcol = (wv & 1) * (NJ * 16);

    for (int kk = 0; kk < kdim; kk += 64) {
#pragma unroll
        for (int iss = 0; iss < 4; ++iss) {  // A: 128x64 bf16 = 16KB = 1024 chunks
            int p = iss * 256 + tid;
            int row = p >> 3, c = p & 7, cs = c ^ (row & 7);
            gload_lds16(&A[(size_t)(rowBase + row) * lda + kk + cs * 8], (char*)ldsA + p * 16);
        }
#pragma unroll
        for (int iss = 0; iss < NJ; ++iss) {  // B: (NJ*32)x64 bf16
            int p = iss * 256 + tid;
            int row = p >> 3, c = p & 7, cs = c ^ (row & 7);
            gload_lds16(&Bm[(size_t)(colBase + row) * ldb + kk + cs * 8], (char*)ldsB + p * 16);
        }
        __syncthreads();
#pragma unroll
        for (int kc = 0; kc < 2; ++kc) {
            short8v av[4], bv[NJ];
#pragma unroll
            for (int i = 0; i < 4; ++i) {
                int row = wrow + i * 16 + lr;
                int phys = row * 128 + ((kc * 4 + lg) ^ (row & 7)) * 16;
                av[i] = *(const short8v*)((const char*)ldsA + phys);
            }
#pragma unroll
            for (int j = 0; j < NJ; ++j) {
                int row = wcol + j * 16 + lr;
                int phys = row * 128 + ((kc * 4 + lg) ^ (row & 7)) * 16;
                bv[j] = *(const short8v*)((const char*)ldsB + phys);
            }
#pragma unroll
            for (int i = 0; i < 4; ++i)
#pragma unroll
                for (int j = 0; j < NJ; ++j)
                    acc[i][j] = __builtin_amdgcn_mfma_f32_16x16x32_bf16(av[i], bv[j], acc[i][j], 0, 0, 0);
        }
        __syncthreads();
    }
}

#define GEMM_SETUP(NJ)                                                           \
    __shared__ unsigned short ldsA[128 * 64];                                    \
    __shared__ unsigned short ldsB[NJ * 32 * 64];                                \
    const int tid = threadIdx.x, lane = tid & 63, wv = tid >> 6;                 \
    const int lr = lane & 15, lg = lane >> 4;                                    \
    const int row0 = blockIdx.x * 128 + (wv >> 1) * 64;                          \
    const int col0 = blockIdx.y * (NJ * 32) + (wv & 1) * (NJ * 16);              \
    f32x4 acc[4][NJ];                                                            \
    _Pragma("unroll") for (int i = 0; i < 4; ++i)                                \
        _Pragma("unroll") for (int j = 0; j < NJ; ++j)                           \
            acc[i][j] = (f32x4){0.f, 0.f, 0.f, 0.f};

// ---------------- K1: Q/K projection (BN=128) ----------------
__global__ __launch_bounds__(256) void mm_proj(const unsigned short* __restrict__ XB,
                                               const unsigned short* __restrict__ WCB,
                                               unsigned short* __restrict__ Qb,
                                               unsigned short* __restrict__ Kb) {
    GEMM_SETUP(4)
    gemm_core<4>(XB, 1024, WCB, 1024, 1024, blockIdx.x * 128, blockIdx.y * 128, ldsA, ldsB, acc);
    unsigned short* dst = (col0 < 1024) ? Qb : Kb;
    const int cbase = col0 & 1023;
#pragma unroll
    for (int i = 0; i < 4; ++i)
#pragma unroll
        for (int r = 0; r < 4; ++r) {
            int rg = row0 + i * 16 + lg * 4 + r;
            int bb = rg >> 10, n = rg & 1023;
#pragma unroll
            for (int j = 0; j < 4; ++j) {
                int c = cbase + j * 16 + lr;
                int h = c >> 6, q = c & 63;
                dst[((size_t)(bb * 16 + h) * 1024 + n) * 64 + q] = f2b(acc[i][j][r]);
            }
        }
}

// ---------------- K6: H = relu(x Whop) (BN=128) ----------------
__global__ __launch_bounds__(256) void mm_hopfwd(const unsigned short* __restrict__ XB,
                                                 const unsigned short* __restrict__ WHTB,
                                                 unsigned short* __restrict__ H,
                                                 float* __restrict__ PH) {
    __shared__ float red[4];
    GEMM_SETUP(4)
    gemm_core<4>(XB, 1024, WHTB, 1024, 1024, blockIdx.x * 128, blockIdx.y * 128, ldsA, ldsB, acc);
    float ss = 0.f;
#pragma unroll
    for (int i = 0; i < 4; ++i)
#pragma unroll
        for (int r = 0; r < 4; ++r) {
            size_t rg = row0 + i * 16 + lg * 4 + r;
#pragma unroll
            for (int j = 0; j < 4; ++j) {
                float hv = fmaxf(acc[i][j][r], 0.f);
                ss += hv * hv;
                H[rg * 4096 + col0 + j * 16 + lr] = f2b(hv);
            }
        }
#pragma unroll
    for (int off = 32; off; off >>= 1) ss += __shfl_down(ss, off);
    if (lane == 0) red[wv] = ss;
    __syncthreads();
    if (tid == 0) PH[blockIdx.y * gridDim.x + blockIdx.x] = red[0] + red[1] + red[2] + red[3];
}

// ---------------- K7: out = -(H Whop^T) (BN=64) ----------------
__global__ __launch_bounds__(256) void mm_hopbwd(const unsigned short* __restrict__ H,
                                                 const unsigned short* __restrict__ WHB,
                                                 float* __restrict__ out) {
    GEMM_SETUP(2)
    gemm_core<2>(H, 4096, WHB, 4096, 4096, blockIdx.x * 128, blockIdx.y * 64, ldsA, ldsB, acc);
#pragma unroll
    for (int i = 0; i < 4; ++i)
#pragma unroll
        for (int r = 0; r < 4; ++r) {
            size_t rg = row0 + i * 16 + lg * 4 + r;
#pragma unroll
            for (int j = 0; j < 2; ++j)
                out[rg * 1024 + col0 + j * 16 + lr] = -acc[i][j][r];
        }
}

// ---------------- K5: out += dQKcat WcatT (BN=64) ----------------
__global__ __launch_bounds__(256) void mm_gradproj(const unsigned short* __restrict__ DQK,
                                                   const unsigned short* __restrict__ WCTB,
                                                   float* __restrict__ out) {
    GEMM_SETUP(2)
    gemm_core<2>(DQK, 2048, WCTB, 2048, 2048, blockIdx.x * 128, blockIdx.y * 64, ldsA, ldsB, acc);
#pragma unroll
    for (int i = 0; i < 4; ++i)
#pragma unroll
        for (int r = 0; r < 4; ++r) {
            size_t rg = row0 + i * 16 + lg * 4 + r;
#pragma unroll
            for (int j = 0; j < 2; ++j) {
                size_t idx = rg * 1024 + col0 + j * 16 + lr;
                out[idx] += acc[i][j][r];
            }
        }
}

// ---------------- transpose Qb/Kb -> QT/KT ----------------
__global__ __launch_bounds__(256) void k_tqk(const unsigned short* __restrict__ Qb,
                                             const unsigned short* __restrict__ Kb,
                                             unsigned short* __restrict__ QT,
                                             unsigned short* __restrict__ KT) {
    __shared__ unsigned short T[64][65];
    const int z = blockIdx.z;
    const unsigned short* src = z ? Kb : Qb;
    unsigned short* dst = z ? KT : QT;
    const int bh = blockIdx.y;
    const int n0 = blockIdx.x * 64;
    const int t = threadIdx.x;
    {
        int row = t >> 3;
        int colc = (t & 7) * 8;
#pragma unroll
        for (int ii = 0; ii < 2; ++ii) {
            int r = row + 32 * ii;
            v8u vv;
            vv.v = *(const short8v*)&src[((size_t)(bh << 10) + n0 + r) * 64 + colc];
#pragma unroll
            for (int j = 0; j < 8; ++j) T[r][colc + j] = vv.u[j];
        }
    }
    __syncthreads();
    {
        int q = t >> 2;
        int nc = (t & 3) * 16;
        unsigned short buf[16];
#pragma unroll
        for (int j = 0; j < 16; ++j) buf[j] = T[nc + j][q];
        *(short8v*)&dst[((size_t)bh * 64 + q) * 1024 + n0 + nc] = *(short8v*)&buf[0];
        *(short8v*)&dst[((size_t)bh * 64 + q) * 1024 + n0 + nc + 8] = *(short8v*)&buf[8];
    }
}

// ---------------- K2: row logsumexp via MFMA ----------------
__global__ __launch_bounds__(256) void k_lse(const unsigned short* __restrict__ Qb,
                                             const unsigned short* __restrict__ Kb,
                                             float* __restrict__ LSE,
                                             float* __restrict__ PL) {
    const int tid = threadIdx.x, lane = tid & 63, wv = tid >> 6;
    const int bh = blockIdx.x, nt = blockIdx.y;
    const int nw = nt * 128 + wv * 32;
    const int lr = lane & 15, lg = lane >> 4;

    short8v qa[2][2];
#pragma unroll
    for (int rb = 0; rb < 2; ++rb)
#pragma unroll
        for (int kc = 0; kc < 2; ++kc)
            qa[rb][kc] = *(const short8v*)&Qb[((size_t)(bh << 10) + nw + rb * 16 + lr) * 64 + kc * 32 + lg * 8];

    float sm[2][4];
#pragma unroll
    for (int rb = 0; rb < 2; ++rb)
#pragma unroll
        for (int r = 0; r < 4; ++r) sm[rb][r] = 0.f;

    for (int mt = 0; mt < 64; ++mt) {
        const unsigned short* kp = &Kb[((size_t)(bh << 10) + mt * 16 + lr) * 64 + lg * 8];
        short8v bk0 = *(const short8v*)kp;
        short8v bk1 = *(const short8v*)(kp + 32);
#pragma unroll
        for (int rb = 0; rb < 2; ++rb) {
            f32x4 s = {0.f, 0.f, 0.f, 0.f};
            s = __builtin_amdgcn_mfma_f32_16x16x32_bf16(qa[rb][0], bk0, s, 0, 0, 0);
            s = __builtin_amdgcn_mfma_f32_16x16x32_bf16(qa[rb][1], bk1, s, 0, 0, 0);
#pragma unroll
            for (int r = 0; r < 4; ++r) sm[rb][r] += __expf(s[r] * BETA);
        }
    }
#pragma unroll
    for (int off = 1; off < 16; off <<= 1)
#pragma unroll
        for (int rb = 0; rb < 2; ++rb)
#pragma unroll
            for (int r = 0; r < 4; ++r) sm[rb][r] += __shfl_xor(sm[rb][r], off);

    float lsum = 0.f;
    if (lr == 0) {
#pragma unroll
        for (int rb = 0; rb < 2; ++rb)
#pragma unroll
            for (int r = 0; r < 4; ++r) {
                float l = __logf(sm[rb][r]);
                LSE[(size_t)(bh << 10) + nw + rb * 16 + lg * 4 + r] = l;
                lsum += l;
            }
    }
    lsum += __shfl_xor(lsum, 16);
    lsum += __shfl_xor(lsum, 32);
    if (lane == 0) PL[(size_t)(bh * 8 + nt) * 4 + wv] = lsum;
}

// ---------------- K3: dQ = -P K -> DQK cols 0..1023 ----------------
__global__ __launch_bounds__(256) void k_dq(const unsigned short* __restrict__ Qb,
                                            const unsigned short* __restrict__ Kb,
                                            const unsigned short* __restrict__ KT,
                                            const float* __restrict__ LSE,
                                            unsigned short* __restrict__ DQK) {
    __shared__ unsigned short P[4][2048];
    const int tid = threadIdx.x, lane = tid & 63, wv = tid >> 6;
    const int bh = blockIdx.x, nt = blockIdx.y;
    const int nw = nt * 128 + wv * 32;
    const int lr = lane & 15, lg = lane >> 4;
    unsigned short* Pw = &P[wv][0];

    short8v qa[2][2];
#pragma unroll
    for (int rb = 0; rb < 2; ++rb)
#pragma unroll
        for (int kc = 0; kc < 2; ++kc)
            qa[rb][kc] = *(const short8v*)&Qb[((size_t)(bh << 10) + nw + rb * 16 + lr) * 64 + kc * 32 + lg * 8];

    float lse_r[2][4];
#pragma unroll
    for (int rb = 0; rb < 2; ++rb)
#pragma unroll
        for (int r = 0; r < 4; ++r)
            lse_r[rb][r] = LSE[(size_t)(bh << 10) + nw + rb * 16 + lg * 4 + r];

    f32x4 dq[2][4];
#pragma unroll
    for (int rb = 0; rb < 2; ++rb)
#pragma unroll
        for (int qb = 0; qb < 4; ++qb) dq[rb][qb] = (f32x4){0.f, 0.f, 0.f, 0.f};

    for (int mt = 0; mt < 16; ++mt) {
        const int m0 = mt * 64;
#pragma unroll
        for (int ct = 0; ct < 4; ++ct) {
            const unsigned short* kp = &Kb[((size_t)(bh << 10) + m0 + ct * 16 + lr) * 64 + lg * 8];
            short8v bk0 = *(const short8v*)kp;
            short8v bk1 = *(const short8v*)(kp + 32);
#pragma unroll
            for (int rb = 0; rb < 2; ++rb) {
                f32x4 s = {0.f, 0.f, 0.f, 0.f};
                s = __builtin_amdgcn_mfma_f32_16x16x32_bf16(qa[rb][0], bk0, s, 0, 0, 0);
                s = __builtin_amdgcn_mfma_f32_16x16x32_bf16(qa[rb][1], bk1, s, 0, 0, 0);
#pragma unroll
                for (int r = 0; r < 4; ++r) {
                    float p = __expf(s[r] * BETA - lse_r[rb][r]);
                    int row = rb * 16 + lg * 4 + r;
                    int off = (row * 64 + ct * 16 + lr) ^ ((row & 7) << 3);
                    Pw[off] = f2b(p);
                }
            }
        }
        short8v pa[2][2];
#pragma unroll
        for (int rb = 0; rb < 2; ++rb) {
            int row = rb * 16 + lr;
#pragma unroll
            for (int kc = 0; kc < 2; ++kc) {
                int off = (row * 64 + kc * 32 + lg * 8) ^ ((row & 7) << 3);
                pa[rb][kc] = *(const short8v*)&Pw[off];
            }
        }
#pragma unroll
        for (int qb = 0; qb < 4; ++qb) {
            const unsigned short* kp = &KT[((size_t)bh * 64 + qb * 16 + lr) * 1024 + m0 + lg * 8];
            short8v b0 = *(const short8v*)kp;
            short8v b1 = *(const short8v*)(kp + 32);
#pragma unroll
            for (int rb = 0; rb < 2; ++rb) {
                dq[rb][qb] = __builtin_amdgcn_mfma_f32_16x16x32_bf16(pa[rb][0], b0, dq[rb][qb], 0, 0, 0);
                dq[rb][qb] = __builtin_amdgcn_mfma_f32_16x16x32_bf16(pa[rb][1], b1, dq[rb][qb], 0, 0, 0);
            }
        }
    }
    const int b = bh >> 4, h = bh & 15;
#pragma unroll
    for (int rb = 0; rb < 2; ++rb)
#pragma unroll
        for (int qb = 0; qb < 4; ++qb)
#pragma unroll
            for (int r = 0; r < 4; ++r)
                DQK[((size_t)(b << 10) + nw + rb * 16 + lg * 4 + r) * 2048 + h * 64 + qb * 16 + lr] = f2b(-dq[rb][qb][r]);
}

// ---------------- K4: dK = -P^T Q -> DQK cols 1024..2047 ----------------
__global__ __launch_bounds__(256) void k_dk(const unsigned short* __restrict__ Qb,
                                            const unsigned short* __restrict__ Kb,
                                            const unsigned short* __restrict__ QT,
                                            const float* __restrict__ LSE,
                                            unsigned short* __restrict__ DQK) {
    __shared__ unsigned short P[4][2048];
    const int tid = threadIdx.x, lane = tid & 63, wv = tid >> 6;
    const int bh = blockIdx.x, mt = blockIdx.y;
    const int mw = mt * 128 + wv * 32;
    const int lr = lane & 15, lg = lane >> 4;
    unsigned short* Pw = &P[wv][0];

    short8v ka[2][2];
#pragma unroll
    for (int rb = 0; rb < 2; ++rb)
#pragma unroll
        for (int kc = 0; kc < 2; ++kc)
            ka[rb][kc] = *(const short8v*)&Kb[((size_t)(bh << 10) + mw + rb * 16 + lr) * 64 + kc * 32 + lg * 8];

    f32x4 dk[2][4];
#pragma unroll
    for (int rb = 0; rb < 2; ++rb)
#pragma unroll
        for (int qb = 0; qb < 4; ++qb) dk[rb][qb] = (f32x4){0.f, 0.f, 0.f, 0.f};

    for (int ntl = 0; ntl < 16; ++ntl) {
        const int n0 = ntl * 64;
#pragma unroll
        for (int ct = 0; ct < 4; ++ct) {
            const unsigned short* qp = &Qb[((size_t)(bh << 10) + n0 + ct * 16 + lr) * 64 + lg * 8];
            short8v bq0 = *(const short8v*)qp;
            short8v bq1 = *(const short8v*)(qp + 32);
            float lse_c = LSE[(size_t)(bh << 10) + n0 + ct * 16 + lr];
#pragma unroll
            for (int rb = 0; rb < 2; ++rb) {
                f32x4 s = {0.f, 0.f, 0.f, 0.f};
                s = __builtin_amdgcn_mfma_f32_16x16x32_bf16(ka[rb][0], bq0, s, 0, 0, 0);
                s = __builtin_amdgcn_mfma_f32_16x16x32_bf16(ka[rb][1], bq1, s, 0, 0, 0);
#pragma unroll
                for (int r = 0; r < 4; ++r) {
                    float p = __expf(s[r] * BETA - lse_c);
                    int row = rb * 16 + lg * 4 + r;
                    int off = (row * 64 + ct * 16 + lr) ^ ((row & 7) << 3);
                    Pw[off] = f2b(p);
                }
            }
        }
        short8v pa[2][2];
#pragma unroll
        for (int rb = 0; rb < 2; ++rb) {
            int row = rb * 16 + lr;
#pragma unroll
            for (int kc = 0; kc < 2; ++kc) {
                int off = (row * 64 + kc * 32 + lg * 8) ^ ((row & 7) << 3);
                pa[rb][kc] = *(const short8v*)&Pw[off];
            }
        }
#pragma unroll
        for (int qb = 0; qb < 4; ++qb) {
            const unsigned short* qp = &QT[((size_t)bh * 64 + qb * 16 + lr) * 1024 + n0 + lg * 8];
            short8v b0 = *(const short8v*)qp;
            short8v b1 = *(const short8v*)(qp + 32);
#pragma unroll
            for (int rb = 0; rb < 2; ++rb) {
                dk[rb][qb] = __builtin_amdgcn_mfma_f32_16x16x32_bf16(pa[rb][0], b0, dk[rb][qb], 0, 0, 0);
                dk[rb][qb] = __builtin_amdgcn_mfma_f32_16x16x32_bf16(pa[rb][1], b1, dk[rb][qb], 0, 0, 0);
            }
        }
    }
    const int b = bh >> 4, h = bh & 15;
#pragma unroll
    for (int rb = 0; rb < 2; ++rb)
#pragma unroll
        for (int qb = 0; qb < 4; ++qb)
#pragma unroll
            for (int r = 0; r < 4; ++r)
                DQK[((size_t)(b << 10) + mw + rb * 16 + lg * 4 + r) * 2048 + 1024 + h * 64 + qb * 16 + lr] = f2b(-dk[rb][qb][r]);
}

// ---------------- K8: finalize energy ----------------
__global__ __launch_bounds__(256) void k_fin(const float* __restrict__ pl,
                                             const float* __restrict__ ph,
                                             float* __restrict__ out) {
    const int tid = threadIdx.x;
    float s1 = 0.f, s2 = 0.f;
    for (int i = tid; i < 2048; i += 256) s1 += pl[i];
    for (int i = tid; i < 1024; i += 256) s2 += ph[i];
#pragma unroll
    for (int off = 32; off; off >>= 1) {
        s1 += __shfl_down(s1, off);
        s2 += __shfl_down(s2, off);
    }
    __shared__ float r1[4], r2[4];
    if ((tid & 63) == 0) { r1[tid >> 6] = s1; r2[tid >> 6] = s2; }
    __syncthreads();
    if (tid == 0) {
        float S1 = r1[0] + r1[1] + r1[2] + r1[3];
        float S2 = r2[0] + r2[1] + r2[2] + r2[3];
        out[(size_t)4194304] = -INV_BETA * S1 - 0.5f * S2;
    }
}

extern "C" void kernel_launch(void* const* d_in, const int* in_sizes, int n_in,
                              void* d_out, int out_size, void* d_ws, size_t ws_size,
                              hipStream_t stream) {
    (void)in_sizes; (void)n_in; (void)out_size; (void)ws_size;
    const float* x    = (const float*)d_in[0];
    const float* Wq   = (const float*)d_in[1];
    const float* Wk   = (const float*)d_in[2];
    const float* Whop = (const float*)d_in[3];
    float* out = (float*)d_out;
    float* ws = (float*)d_ws;

    unsigned short* XB   = (unsigned short*)(ws + OFF_XB);
    unsigned short* WCB  = (unsigned short*)(ws + OFF_WCB);
    unsigned short* WCTB = (unsigned short*)(ws + OFF_WCTB);
    unsigned short* WHB  = (unsigned short*)(ws + OFF_WHB);
    unsigned short* WHTB = (unsigned short*)(ws + OFF_WHTB);
    unsigned short* H    = (unsigned short*)(ws + OFF_H);
    unsigned short* Qb   = (unsigned short*)(ws + OFF_QB);
    unsigned short* Kb   = (unsigned short*)(ws + OFF_KB);
    unsigned short* QT   = (unsigned short*)(ws + OFF_QT);
    unsigned short* KT   = (unsigned short*)(ws + OFF_KT);
    unsigned short* DQK  = (unsigned short*)(ws + OFF_DQK);
    float* LSE = ws + OFF_LSE;
    float* PL  = ws + OFF_PL;
    float* PH  = ws + OFF_PH;

    dim3 blk(256);
    k_cast<<<dim3(4096), blk, 0, stream>>>(x, XB, 1048576);
    k_cast<<<dim3(1024), blk, 0, stream>>>(Wq, WCB, 262144);
    k_cast<<<dim3(1024), blk, 0, stream>>>(Wk, WCB + 1048576, 262144);
    k_cast<<<dim3(4096), blk, 0, stream>>>(Whop, WHB, 1048576);
    k_tcatb<<<dim3(64, 32), dim3(32, 8), 0, stream>>>(Wq, Wk, WCTB);
    k_thopb<<<dim3(128, 32), dim3(32, 8), 0, stream>>>(Whop, WHTB);

    mm_proj<<<dim3(32, 16), blk, 0, stream>>>(XB, WCB, Qb, Kb);
    k_tqk<<<dim3(16, 64, 2), blk, 0, stream>>>(Qb, Kb, QT, KT);
    k_lse<<<dim3(64, 8), blk, 0, stream>>>(Qb, Kb, LSE, PL);
    k_dq<<<dim3(64, 8), blk, 0, stream>>>(Qb, Kb, KT, LSE, DQK);
    k_dk<<<dim3(64, 8), blk, 0, stream>>>(Qb, Kb, QT, LSE, DQK);

    mm_hopfwd<<<dim3(32, 32), blk, 0, stream>>>(XB, WHTB, H, PH);
    mm_hopbwd<<<dim3(32, 16), blk, 0, stream>>>(H, WHB, out);
    mm_gradproj<<<dim3(32, 16), blk, 0, stream>>>(DQK, WCTB, out);
    k_fin<<<dim3(1), blk, 0, stream>>>(PL, PH, out);
}

// Round 6
// 327.952 us; speedup vs baseline: 19.9300x; 1.2722x over previous
//
#include <hip/hip_runtime.h>
#include <hip/hip_bf16.h>
#include <math.h>

#define BETA 0.125f
#define INV_BETA 8.0f

typedef __attribute__((ext_vector_type(8))) short short8v;
typedef __attribute__((ext_vector_type(4))) float f32x4;
typedef union { short8v v; unsigned short u[8]; } v8u;

// ws layout (float units)
#define OFF_XB   0u          // bf16 x      [4096][1024]
#define OFF_WCB  2097152u    // bf16 Wcat   [2048][1024]
#define OFF_WCTB 3145728u    // bf16 WcatT  [1024][2048]
#define OFF_WHB  4194304u    // bf16 Whop   [1024][4096]
#define OFF_WHTB 6291456u    // bf16 WhopT  [4096][1024]
#define OFF_H    8388608u    // bf16 H      [4096][4096]
#define OFF_QB   16777216u   // bf16 Qb     [64][1024][64]
#define OFF_KB   18874368u   // bf16 Kb
#define OFF_QT   20971520u   // bf16 QT     [64][64][1024]
#define OFF_KT   23068672u   // bf16 KT
#define OFF_DQK  25165824u   // bf16 dQKcat [4096][2048]
#define OFF_LSE  29360128u   // f32 [65536]
#define OFF_PL   29425664u   // f32 [2048]
#define OFF_PH   29427712u   // f32 [1024]

__device__ __forceinline__ unsigned short f2b(float f) {
    unsigned u = __float_as_uint(f);
    return (unsigned short)((u + 0x7fffu + ((u >> 16) & 1u)) >> 16);
}

__device__ __forceinline__ void gload_lds16(const unsigned short* g, void* l) {
    __builtin_amdgcn_global_load_lds(
        (const __attribute__((address_space(1))) unsigned int*)g,
        (__attribute__((address_space(3))) unsigned int*)l, 16, 0, 0);
}

// ---------------- bf16 cast ----------------
__global__ __launch_bounds__(256) void k_cast(const float* __restrict__ src,
                                              unsigned short* __restrict__ dst, int n4) {
    int i = blockIdx.x * 256 + threadIdx.x;
    if (i < n4) {
        float4 v = ((const float4*)src)[i];
        ushort4 o;
        o.x = f2b(v.x); o.y = f2b(v.y); o.z = f2b(v.z); o.w = f2b(v.w);
        ((ushort4*)dst)[i] = o;
    }
}

// ---------------- bf16 transposes ----------------
__global__ void k_tcatb(const float* __restrict__ Wq, const float* __restrict__ Wk,
                        unsigned short* __restrict__ WCTB) {
    __shared__ float t[32][33];
    int j0 = blockIdx.x * 32, d0 = blockIdx.y * 32;
    int tx = threadIdx.x, ty = threadIdx.y;
#pragma unroll
    for (int i = 0; i < 4; ++i) {
        int j = j0 + ty + 8 * i;
        const float* src = (j < 1024) ? (Wq + (size_t)j * 1024) : (Wk + (size_t)(j - 1024) * 1024);
        t[ty + 8 * i][tx] = src[d0 + tx];
    }
    __syncthreads();
#pragma unroll
    for (int i = 0; i < 4; ++i)
        WCTB[(size_t)(d0 + ty + 8 * i) * 2048 + j0 + tx] = f2b(t[tx][ty + 8 * i]);
}

__global__ void k_thopb(const float* __restrict__ Whop, unsigned short* __restrict__ WHTB) {
    __shared__ float t[32][33];
    int e0 = blockIdx.x * 32, d0 = blockIdx.y * 32;
    int tx = threadIdx.x, ty = threadIdx.y;
#pragma unroll
    for (int i = 0; i < 4; ++i)
        t[ty + 8 * i][tx] = Whop[(size_t)(d0 + ty + 8 * i) * 4096 + e0 + tx];
    __syncthreads();
#pragma unroll
    for (int i = 0; i < 4; ++i)
        WHTB[(size_t)(e0 + ty + 8 * i) * 1024 + d0 + tx] = f2b(t[tx][ty + 8 * i]);
}

// ============ m97-structure GEMM core (NT: A[M][K] x B[N][K]) ============
template <int NJ>
__device__ __forceinline__ void gemm_core(const unsigned short* __restrict__ A, int lda,
                                          const unsigned short* __restrict__ Bm, int ldb,
                                          int kdim, int rowBase, int colBase,
                                          unsigned short* ldsA, unsigned short* ldsB,
                                          f32x4 (&acc)[4][NJ]) {
    const int tid = threadIdx.x, lane = tid & 63;
    const int wv = tid >> 6;
    const int lr = lane & 15, lg = lane >> 4;
    const int wrow = (wv >> 1) * 64;
    const int wcol = (wv & 1) * (NJ * 16);

    for (int kk = 0; kk < kdim; kk += 64) {
#pragma unroll
        for (int iss = 0; iss < 4; ++iss) {
            int p = iss * 256 + tid;
            int row = p >> 3, c = p & 7, cs = c ^ (row & 7);
            gload_lds16(&A[(size_t)(rowBase + row) * lda + kk + cs * 8], (char*)ldsA + p * 16);
        }
#pragma unroll
        for (int iss = 0; iss < NJ; ++iss) {
            int p = iss * 256 + tid;
            int row = p >> 3, c = p & 7, cs = c ^ (row & 7);
            gload_lds16(&Bm[(size_t)(colBase + row) * ldb + kk + cs * 8], (char*)ldsB + p * 16);
        }
        __syncthreads();
#pragma unroll
        for (int kc = 0; kc < 2; ++kc) {
            short8v av[4], bv[NJ];
#pragma unroll
            for (int i = 0; i < 4; ++i) {
                int row = wrow + i * 16 + lr;
                int phys = row * 128 + ((kc * 4 + lg) ^ (row & 7)) * 16;
                av[i] = *(const short8v*)((const char*)ldsA + phys);
            }
#pragma unroll
            for (int j = 0; j < NJ; ++j) {
                int row = wcol + j * 16 + lr;
                int phys = row * 128 + ((kc * 4 + lg) ^ (row & 7)) * 16;
                bv[j] = *(const short8v*)((const char*)ldsB + phys);
            }
#pragma unroll
            for (int i = 0; i < 4; ++i)
#pragma unroll
                for (int j = 0; j < NJ; ++j)
                    acc[i][j] = __builtin_amdgcn_mfma_f32_16x16x32_bf16(av[i], bv[j], acc[i][j], 0, 0, 0);
        }
        __syncthreads();
    }
}

#define GEMM_SETUP(NJ)                                                           \
    __shared__ unsigned short ldsA[128 * 64];                                    \
    __shared__ unsigned short ldsB[NJ * 32 * 64];                                \
    const int tid = threadIdx.x, lane = tid & 63, wv = tid >> 6;                 \
    const int lr = lane & 15, lg = lane >> 4;                                    \
    const int row0 = blockIdx.x * 128 + (wv >> 1) * 64;                          \
    const int col0 = blockIdx.y * (NJ * 32) + (wv & 1) * (NJ * 16);              \
    f32x4 acc[4][NJ];                                                            \
    _Pragma("unroll") for (int i = 0; i < 4; ++i)                                \
        _Pragma("unroll") for (int j = 0; j < NJ; ++j)                           \
            acc[i][j] = (f32x4){0.f, 0.f, 0.f, 0.f};

// ---------------- K1: Q/K projection (BN=128) ----------------
__global__ __launch_bounds__(256) void mm_proj(const unsigned short* __restrict__ XB,
                                               const unsigned short* __restrict__ WCB,
                                               unsigned short* __restrict__ Qb,
                                               unsigned short* __restrict__ Kb) {
    GEMM_SETUP(4)
    gemm_core<4>(XB, 1024, WCB, 1024, 1024, blockIdx.x * 128, blockIdx.y * 128, ldsA, ldsB, acc);
    unsigned short* dst = (col0 < 1024) ? Qb : Kb;
    const int cbase = col0 & 1023;
#pragma unroll
    for (int i = 0; i < 4; ++i)
#pragma unroll
        for (int r = 0; r < 4; ++r) {
            int rg = row0 + i * 16 + lg * 4 + r;
            int bb = rg >> 10, n = rg & 1023;
#pragma unroll
            for (int j = 0; j < 4; ++j) {
                int c = cbase + j * 16 + lr;
                int h = c >> 6, q = c & 63;
                dst[((size_t)(bb * 16 + h) * 1024 + n) * 64 + q] = f2b(acc[i][j][r]);
            }
        }
}

// ---------------- K6: H = relu(x Whop) (BN=128) ----------------
__global__ __launch_bounds__(256) void mm_hopfwd(const unsigned short* __restrict__ XB,
                                                 const unsigned short* __restrict__ WHTB,
                                                 unsigned short* __restrict__ H,
                                                 float* __restrict__ PH) {
    __shared__ float red[4];
    GEMM_SETUP(4)
    gemm_core<4>(XB, 1024, WHTB, 1024, 1024, blockIdx.x * 128, blockIdx.y * 128, ldsA, ldsB, acc);
    float ss = 0.f;
#pragma unroll
    for (int i = 0; i < 4; ++i)
#pragma unroll
        for (int r = 0; r < 4; ++r) {
            size_t rg = row0 + i * 16 + lg * 4 + r;
#pragma unroll
            for (int j = 0; j < 4; ++j) {
                float hv = fmaxf(acc[i][j][r], 0.f);
                ss += hv * hv;
                H[rg * 4096 + col0 + j * 16 + lr] = f2b(hv);
            }
        }
#pragma unroll
    for (int off = 32; off; off >>= 1) ss += __shfl_down(ss, off);
    if (lane == 0) red[wv] = ss;
    __syncthreads();
    if (tid == 0) PH[blockIdx.y * gridDim.x + blockIdx.x] = red[0] + red[1] + red[2] + red[3];
}

// ---------------- K7: out = -(H Whop^T) (BN=64) ----------------
__global__ __launch_bounds__(256) void mm_hopbwd(const unsigned short* __restrict__ H,
                                                 const unsigned short* __restrict__ WHB,
                                                 float* __restrict__ out) {
    GEMM_SETUP(2)
    gemm_core<2>(H, 4096, WHB, 4096, 4096, blockIdx.x * 128, blockIdx.y * 64, ldsA, ldsB, acc);
#pragma unroll
    for (int i = 0; i < 4; ++i)
#pragma unroll
        for (int r = 0; r < 4; ++r) {
            size_t rg = row0 + i * 16 + lg * 4 + r;
#pragma unroll
            for (int j = 0; j < 2; ++j)
                out[rg * 1024 + col0 + j * 16 + lr] = -acc[i][j][r];
        }
}

// ---------------- K5: out += dQKcat WcatT (BN=64) ----------------
__global__ __launch_bounds__(256) void mm_gradproj(const unsigned short* __restrict__ DQK,
                                                   const unsigned short* __restrict__ WCTB,
                                                   float* __restrict__ out) {
    GEMM_SETUP(2)
    gemm_core<2>(DQK, 2048, WCTB, 2048, 2048, blockIdx.x * 128, blockIdx.y * 64, ldsA, ldsB, acc);
#pragma unroll
    for (int i = 0; i < 4; ++i)
#pragma unroll
        for (int r = 0; r < 4; ++r) {
            size_t rg = row0 + i * 16 + lg * 4 + r;
#pragma unroll
            for (int j = 0; j < 2; ++j) {
                size_t idx = rg * 1024 + col0 + j * 16 + lr;
                out[idx] += acc[i][j][r];
            }
        }
}

// ---------------- transpose Qb/Kb -> QT/KT ----------------
__global__ __launch_bounds__(256) void k_tqk(const unsigned short* __restrict__ Qb,
                                             const unsigned short* __restrict__ Kb,
                                             unsigned short* __restrict__ QT,
                                             unsigned short* __restrict__ KT) {
    __shared__ unsigned short T[64][65];
    const int z = blockIdx.z;
    const unsigned short* src = z ? Kb : Qb;
    unsigned short* dst = z ? KT : QT;
    const int bh = blockIdx.y;
    const int n0 = blockIdx.x * 64;
    const int t = threadIdx.x;
    {
        int row = t >> 3;
        int colc = (t & 7) * 8;
#pragma unroll
        for (int ii = 0; ii < 2; ++ii) {
            int r = row + 32 * ii;
            v8u vv;
            vv.v = *(const short8v*)&src[((size_t)(bh << 10) + n0 + r) * 64 + colc];
#pragma unroll
            for (int j = 0; j < 8; ++j) T[r][colc + j] = vv.u[j];
        }
    }
    __syncthreads();
    {
        int q = t >> 2;
        int nc = (t & 3) * 16;
        unsigned short buf[16];
#pragma unroll
        for (int j = 0; j < 16; ++j) buf[j] = T[nc + j][q];
        *(short8v*)&dst[((size_t)bh * 64 + q) * 1024 + n0 + nc] = *(short8v*)&buf[0];
        *(short8v*)&dst[((size_t)bh * 64 + q) * 1024 + n0 + nc + 8] = *(short8v*)&buf[8];
    }
}

// ---------------- K3: fused lse + dQ (staged, 2-phase) ----------------
// dq_unnorm = sum_m exp(beta*s) K_m ; row-sum online; dq = dq_unnorm / sm.
// Writes DQK cols 0..1023, LSE = log(sm), PL energy partials.
__global__ __launch_bounds__(256) void k_dq(const unsigned short* __restrict__ Qb,
                                            const unsigned short* __restrict__ Kb,
                                            const unsigned short* __restrict__ KT,
                                            float* __restrict__ LSE,
                                            float* __restrict__ PL,
                                            unsigned short* __restrict__ DQK) {
    __shared__ unsigned short Ktile[2][64 * 64];
    __shared__ unsigned short Ttile[2][64 * 64];
    __shared__ unsigned short P[4][2048];
    const int tid = threadIdx.x, lane = tid & 63, wv = tid >> 6;
    const int bh = blockIdx.x, nt = blockIdx.y;
    const int nw = nt * 128 + wv * 32;
    const int lr = lane & 15, lg = lane >> 4;
    unsigned short* Pw = &P[wv][0];

    auto stage = [&](int buf, int m0) {
#pragma unroll
        for (int iss = 0; iss < 2; ++iss) {
            int p = iss * 256 + tid;
            int row = p >> 3, c = p & 7, cs = c ^ (row & 7);
            gload_lds16(&Kb[((size_t)(bh << 10) + m0 + row) * 64 + cs * 8],
                        (char*)&Ktile[buf][0] + p * 16);
            gload_lds16(&KT[((size_t)bh * 64 + row) * 1024 + m0 + cs * 8],
                        (char*)&Ttile[buf][0] + p * 16);
        }
    };

    short8v qa[2][2];
#pragma unroll
    for (int rb = 0; rb < 2; ++rb)
#pragma unroll
        for (int kc = 0; kc < 2; ++kc)
            qa[rb][kc] = *(const short8v*)&Qb[((size_t)(bh << 10) + nw + rb * 16 + lr) * 64 + kc * 32 + lg * 8];

    float sm[2][4];
    f32x4 dq[2][4];
#pragma unroll
    for (int rb = 0; rb < 2; ++rb) {
#pragma unroll
        for (int r = 0; r < 4; ++r) sm[rb][r] = 0.f;
#pragma unroll
        for (int qb = 0; qb < 4; ++qb) dq[rb][qb] = (f32x4){0.f, 0.f, 0.f, 0.f};
    }

    stage(0, 0);
    __syncthreads();
    int buf = 0;
    for (int mt = 0; mt < 16; ++mt) {
        if (mt < 15) stage(buf ^ 1, (mt + 1) * 64);
        const char* Kt = (const char*)&Ktile[buf][0];
        const char* Tt = (const char*)&Ttile[buf][0];
#pragma unroll
        for (int ct = 0; ct < 4; ++ct) {
            int brow = ct * 16 + lr;
            short8v bk0 = *(const short8v*)(Kt + brow * 128 + ((lg) ^ (brow & 7)) * 16);
            short8v bk1 = *(const short8v*)(Kt + brow * 128 + ((lg + 4) ^ (brow & 7)) * 16);
#pragma unroll
            for (int rb = 0; rb < 2; ++rb) {
                f32x4 s = {0.f, 0.f, 0.f, 0.f};
                s = __builtin_amdgcn_mfma_f32_16x16x32_bf16(qa[rb][0], bk0, s, 0, 0, 0);
                s = __builtin_amdgcn_mfma_f32_16x16x32_bf16(qa[rb][1], bk1, s, 0, 0, 0);
#pragma unroll
                for (int r = 0; r < 4; ++r) {
                    float p = __expf(s[r] * BETA);
                    sm[rb][r] += p;
                    int row = rb * 16 + lg * 4 + r;
                    int off = (row * 64 + ct * 16 + lr) ^ ((row & 7) << 3);
                    Pw[off] = f2b(p);
                }
            }
        }
        short8v pa[2][2];
#pragma unroll
        for (int rb = 0; rb < 2; ++rb) {
            int row = rb * 16 + lr;
#pragma unroll
            for (int kc = 0; kc < 2; ++kc) {
                int off = (row * 64 + kc * 32 + lg * 8) ^ ((row & 7) << 3);
                pa[rb][kc] = *(const short8v*)&Pw[off];
            }
        }
#pragma unroll
        for (int qb = 0; qb < 4; ++qb) {
            int brow = qb * 16 + lr;
            short8v b0 = *(const short8v*)(Tt + brow * 128 + ((lg) ^ (brow & 7)) * 16);
            short8v b1 = *(const short8v*)(Tt + brow * 128 + ((lg + 4) ^ (brow & 7)) * 16);
#pragma unroll
            for (int rb = 0; rb < 2; ++rb) {
                dq[rb][qb] = __builtin_amdgcn_mfma_f32_16x16x32_bf16(pa[rb][0], b0, dq[rb][qb], 0, 0, 0);
                dq[rb][qb] = __builtin_amdgcn_mfma_f32_16x16x32_bf16(pa[rb][1], b1, dq[rb][qb], 0, 0, 0);
            }
        }
        __syncthreads();
        buf ^= 1;
    }

    // row-sum reduce across the 16 lr lanes
#pragma unroll
    for (int off = 1; off < 16; off <<= 1)
#pragma unroll
        for (int rb = 0; rb < 2; ++rb)
#pragma unroll
            for (int r = 0; r < 4; ++r) sm[rb][r] += __shfl_xor(sm[rb][r], off);

    const int b = bh >> 4, h = bh & 15;
#pragma unroll
    for (int rb = 0; rb < 2; ++rb) {
#pragma unroll
        for (int r = 0; r < 4; ++r) {
            float inv = 1.0f / sm[rb][r];
#pragma unroll
            for (int qb = 0; qb < 4; ++qb)
                DQK[((size_t)(b << 10) + nw + rb * 16 + lg * 4 + r) * 2048 + h * 64 + qb * 16 + lr] =
                    f2b(-dq[rb][qb][r] * inv);
        }
    }

    float lsum = 0.f;
    if (lr == 0) {
#pragma unroll
        for (int rb = 0; rb < 2; ++rb)
#pragma unroll
            for (int r = 0; r < 4; ++r) {
                float l = __logf(sm[rb][r]);
                LSE[(size_t)(bh << 10) + nw + rb * 16 + lg * 4 + r] = l;
                lsum += l;
            }
    }
    lsum += __shfl_xor(lsum, 16);
    lsum += __shfl_xor(lsum, 32);
    if (lane == 0) PL[(size_t)(bh * 8 + nt) * 4 + wv] = lsum;
}

// ---------------- K4: dK = -P^T Q (staged, 2-phase) -> DQK cols 1024..2047 ----------------
__global__ __launch_bounds__(256) void k_dk(const unsigned short* __restrict__ Qb,
                                            const unsigned short* __restrict__ Kb,
                                            const unsigned short* __restrict__ QT,
                                            const float* __restrict__ LSE,
                                            unsigned short* __restrict__ DQK) {
    __shared__ unsigned short Qtile[2][64 * 64];
    __shared__ unsigned short Ttile[2][64 * 64];
    __shared__ unsigned short P[4][2048];
    const int tid = threadIdx.x, lane = tid & 63, wv = tid >> 6;
    const int bh = blockIdx.x, mt = blockIdx.y;
    const int mw = mt * 128 + wv * 32;
    const int lr = lane & 15, lg = lane >> 4;
    unsigned short* Pw = &P[wv][0];

    auto stage = [&](int buf, int n0) {
#pragma unroll
        for (int iss = 0; iss < 2; ++iss) {
            int p = iss * 256 + tid;
            int row = p >> 3, c = p & 7, cs = c ^ (row & 7);
            gload_lds16(&Qb[((size_t)(bh << 10) + n0 + row) * 64 + cs * 8],
                        (char*)&Qtile[buf][0] + p * 16);
            gload_lds16(&QT[((size_t)bh * 64 + row) * 1024 + n0 + cs * 8],
                        (char*)&Ttile[buf][0] + p * 16);
        }
    };

    short8v ka[2][2];
#pragma unroll
    for (int rb = 0; rb < 2; ++rb)
#pragma unroll
        for (int kc = 0; kc < 2; ++kc)
            ka[rb][kc] = *(const short8v*)&Kb[((size_t)(bh << 10) + mw + rb * 16 + lr) * 64 + kc * 32 + lg * 8];

    f32x4 dk[2][4];
#pragma unroll
    for (int rb = 0; rb < 2; ++rb)
#pragma unroll
        for (int qb = 0; qb < 4; ++qb) dk[rb][qb] = (f32x4){0.f, 0.f, 0.f, 0.f};

    stage(0, 0);
    __syncthreads();
    int buf = 0;
    for (int ntl = 0; ntl < 16; ++ntl) {
        const int n0 = ntl * 64;
        float lse_c[4];
#pragma unroll
        for (int ct = 0; ct < 4; ++ct)
            lse_c[ct] = LSE[(size_t)(bh << 10) + n0 + ct * 16 + lr];
        if (ntl < 15) stage(buf ^ 1, n0 + 64);
        const char* Qt = (const char*)&Qtile[buf][0];
        const char* Tt = (const char*)&Ttile[buf][0];
#pragma unroll
        for (int ct = 0; ct < 4; ++ct) {
            int brow = ct * 16 + lr;
            short8v bq0 = *(const short8v*)(Qt + brow * 128 + ((lg) ^ (brow & 7)) * 16);
            short8v bq1 = *(const short8v*)(Qt + brow * 128 + ((lg + 4) ^ (brow & 7)) * 16);
#pragma unroll
            for (int rb = 0; rb < 2; ++rb) {
                f32x4 s = {0.f, 0.f, 0.f, 0.f};
                s = __builtin_amdgcn_mfma_f32_16x16x32_bf16(ka[rb][0], bq0, s, 0, 0, 0);
                s = __builtin_amdgcn_mfma_f32_16x16x32_bf16(ka[rb][1], bq1, s, 0, 0, 0);
#pragma unroll
                for (int r = 0; r < 4; ++r) {
                    float p = __expf(s[r] * BETA - lse_c[ct]);
                    int row = rb * 16 + lg * 4 + r;
                    int off = (row * 64 + ct * 16 + lr) ^ ((row & 7) << 3);
                    Pw[off] = f2b(p);
                }
            }
        }
        short8v pa[2][2];
#pragma unroll
        for (int rb = 0; rb < 2; ++rb) {
            int row = rb * 16 + lr;
#pragma unroll
            for (int kc = 0; kc < 2; ++kc) {
                int off = (row * 64 + kc * 32 + lg * 8) ^ ((row & 7) << 3);
                pa[rb][kc] = *(const short8v*)&Pw[off];
            }
        }
#pragma unroll
        for (int qb = 0; qb < 4; ++qb) {
            int brow = qb * 16 + lr;
            short8v b0 = *(const short8v*)(Tt + brow * 128 + ((lg) ^ (brow & 7)) * 16);
            short8v b1 = *(const short8v*)(Tt + brow * 128 + ((lg + 4) ^ (brow & 7)) * 16);
#pragma unroll
            for (int rb = 0; rb < 2; ++rb) {
                dk[rb][qb] = __builtin_amdgcn_mfma_f32_16x16x32_bf16(pa[rb][0], b0, dk[rb][qb], 0, 0, 0);
                dk[rb][qb] = __builtin_amdgcn_mfma_f32_16x16x32_bf16(pa[rb][1], b1, dk[rb][qb], 0, 0, 0);
            }
        }
        __syncthreads();
        buf ^= 1;
    }
    const int b = bh >> 4, h = bh & 15;
#pragma unroll
    for (int rb = 0; rb < 2; ++rb)
#pragma unroll
        for (int qb = 0; qb < 4; ++qb)
#pragma unroll
            for (int r = 0; r < 4; ++r)
                DQK[((size_t)(b << 10) + mw + rb * 16 + lg * 4 + r) * 2048 + 1024 + h * 64 + qb * 16 + lr] = f2b(-dk[rb][qb][r]);
}

// ---------------- K8: finalize energy ----------------
__global__ __launch_bounds__(256) void k_fin(const float* __restrict__ pl,
                                             const float* __restrict__ ph,
                                             float* __restrict__ out) {
    const int tid = threadIdx.x;
    float s1 = 0.f, s2 = 0.f;
    for (int i = tid; i < 2048; i += 256) s1 += pl[i];
    for (int i = tid; i < 1024; i += 256) s2 += ph[i];
#pragma unroll
    for (int off = 32; off; off >>= 1) {
        s1 += __shfl_down(s1, off);
        s2 += __shfl_down(s2, off);
    }
    __shared__ float r1[4], r2[4];
    if ((tid & 63) == 0) { r1[tid >> 6] = s1; r2[tid >> 6] = s2; }
    __syncthreads();
    if (tid == 0) {
        float S1 = r1[0] + r1[1] + r1[2] + r1[3];
        float S2 = r2[0] + r2[1] + r2[2] + r2[3];
        out[(size_t)4194304] = -INV_BETA * S1 - 0.5f * S2;
    }
}

extern "C" void kernel_launch(void* const* d_in, const int* in_sizes, int n_in,
                              void* d_out, int out_size, void* d_ws, size_t ws_size,
                              hipStream_t stream) {
    (void)in_sizes; (void)n_in; (void)out_size; (void)ws_size;
    const float* x    = (const float*)d_in[0];
    const float* Wq   = (const float*)d_in[1];
    const float* Wk   = (const float*)d_in[2];
    const float* Whop = (const float*)d_in[3];
    float* out = (float*)d_out;
    float* ws = (float*)d_ws;

    unsigned short* XB   = (unsigned short*)(ws + OFF_XB);
    unsigned short* WCB  = (unsigned short*)(ws + OFF_WCB);
    unsigned short* WCTB = (unsigned short*)(ws + OFF_WCTB);
    unsigned short* WHB  = (unsigned short*)(ws + OFF_WHB);
    unsigned short* WHTB = (unsigned short*)(ws + OFF_WHTB);
    unsigned short* H    = (unsigned short*)(ws + OFF_H);
    unsigned short* Qb   = (unsigned short*)(ws + OFF_QB);
    unsigned short* Kb   = (unsigned short*)(ws + OFF_KB);
    unsigned short* QT   = (unsigned short*)(ws + OFF_QT);
    unsigned short* KT   = (unsigned short*)(ws + OFF_KT);
    unsigned short* DQK  = (unsigned short*)(ws + OFF_DQK);
    float* LSE = ws + OFF_LSE;
    float* PL  = ws + OFF_PL;
    float* PH  = ws + OFF_PH;

    dim3 blk(256);
    k_cast<<<dim3(4096), blk, 0, stream>>>(x, XB, 1048576);
    k_cast<<<dim3(1024), blk, 0, stream>>>(Wq, WCB, 262144);
    k_cast<<<dim3(1024), blk, 0, stream>>>(Wk, WCB + 1048576, 262144);
    k_cast<<<dim3(4096), blk, 0, stream>>>(Whop, WHB, 1048576);
    k_tcatb<<<dim3(64, 32), dim3(32, 8), 0, stream>>>(Wq, Wk, WCTB);
    k_thopb<<<dim3(128, 32), dim3(32, 8), 0, stream>>>(Whop, WHTB);

    mm_proj<<<dim3(32, 16), blk, 0, stream>>>(XB, WCB, Qb, Kb);
    k_tqk<<<dim3(16, 64, 2), blk, 0, stream>>>(Qb, Kb, QT, KT);
    k_dq<<<dim3(64, 8), blk, 0, stream>>>(Qb, Kb, KT, LSE, PL, DQK);
    k_dk<<<dim3(64, 8), blk, 0, stream>>>(Qb, Kb, QT, LSE, DQK);

    mm_hopfwd<<<dim3(32, 32), blk, 0, stream>>>(XB, WHTB, H, PH);
    mm_hopbwd<<<dim3(32, 16), blk, 0, stream>>>(H, WHB, out);
    mm_gradproj<<<dim3(32, 16), blk, 0, stream>>>(DQK, WCTB, out);
    k_fin<<<dim3(1), blk, 0, stream>>>(PL, PH, out);
}